// Round 1
// baseline (19300.337 us; speedup 1.0000x reference)
//
#include <hip/hip_runtime.h>

// GraphConv x2:
//   agg1 = segsum(x[src]->dst); h = relu(agg1@Wr1^T + x@Wq1^T + b1)
//   hr = h@Wr2^T; out = h@Wq2^T + b2 + segsum(hr[src]->dst)
// (layer-2 scatter moved after the GEMM so it runs on 64 feats, not 128)

#define KC 32
#define LDP 132   // 128 + 4 pad: keeps float4 alignment, breaks bank stride

// ---------------- edge scatter-add, 128 feats (32 float4/edge) ----------------
__global__ void scatter_add_f128(const float4* __restrict__ x4,
                                 const int* __restrict__ src,
                                 const int* __restrict__ dst,
                                 float* __restrict__ agg, int E)
{
    int t = blockIdx.x * 256 + threadIdx.x;
    int e = t >> 5;
    if (e >= E) return;
    int f = t & 31;
    int s = src[e];
    int d = dst[e];
    float4 v = x4[s * 32 + f];
    float* p = agg + d * 128 + f * 4;
    atomicAdd(p + 0, v.x);
    atomicAdd(p + 1, v.y);
    atomicAdd(p + 2, v.z);
    atomicAdd(p + 3, v.w);
}

// ---------------- edge scatter-add, 64 feats (16 float4/edge) ----------------
__global__ void scatter_add_f64(const float4* __restrict__ h4,
                                const int* __restrict__ src,
                                const int* __restrict__ dst,
                                float* __restrict__ out, int E)
{
    int t = blockIdx.x * 256 + threadIdx.x;
    int e = t >> 4;
    if (e >= E) return;
    int f = t & 15;
    int s = src[e];
    int d = dst[e];
    float4 v = h4[s * 16 + f];
    float* p = out + d * 64 + f * 4;
    atomicAdd(p + 0, v.x);
    atomicAdd(p + 1, v.y);
    atomicAdd(p + 2, v.z);
    atomicAdd(p + 3, v.w);
}

// ------------- layer 1: h = relu(A1@W1^T + A2@W2^T + bias), 128 out ----------
// block: 256 threads, tile 128 nodes x 128 outs, thread = 8 nodes x 8 outs
__global__ __launch_bounds__(256) void gemm_dual_relu(
    const float* __restrict__ A1, const float* __restrict__ A2,
    const float* __restrict__ W1, const float* __restrict__ W2,
    const float* __restrict__ bias, float* __restrict__ out, int N)
{
    __shared__ float sA[KC][LDP];
    __shared__ float sW[KC][LDP];
    const int tid = threadIdx.x;
    const int ng = tid >> 4;   // node group 0..15 (8 nodes each)
    const int og = tid & 15;   // out  group 0..15 (8 outs each)
    const int n0 = blockIdx.x * 128;

    float acc[8][8];
#pragma unroll
    for (int i = 0; i < 8; ++i)
#pragma unroll
        for (int j = 0; j < 8; ++j) acc[i][j] = 0.f;

#pragma unroll
    for (int chunk = 0; chunk < 8; ++chunk) {
        const float* A = (chunk < 4) ? A1 : A2;
        const float* W = (chunk < 4) ? W1 : W2;
        const int kc = (chunk & 3) * KC;
        // stage A[128n x 32k] -> sA[k][n], W[128o x 32k] -> sW[k][o]
#pragma unroll
        for (int i = 0; i < 4; ++i) {
            int fidx = tid + i * 256;      // float4 index 0..1023
            int r = fidx >> 3;             // row 0..127
            int k4 = fidx & 7;             // which float4 in the 32-k chunk
            int n = n0 + r; if (n >= N) n = N - 1;   // clamp (results masked later)
            float4 va = *(const float4*)(A + (size_t)n * 128 + kc + k4 * 4);
            sA[k4*4+0][r] = va.x; sA[k4*4+1][r] = va.y;
            sA[k4*4+2][r] = va.z; sA[k4*4+3][r] = va.w;
            float4 vw = *(const float4*)(W + (size_t)r * 128 + kc + k4 * 4);
            sW[k4*4+0][r] = vw.x; sW[k4*4+1][r] = vw.y;
            sW[k4*4+2][r] = vw.z; sW[k4*4+3][r] = vw.w;
        }
        __syncthreads();
#pragma unroll
        for (int k = 0; k < KC; ++k) {
            float a[8], w[8];
            *(float4*)&a[0] = *(const float4*)&sA[k][ng*8];
            *(float4*)&a[4] = *(const float4*)&sA[k][ng*8+4];
            *(float4*)&w[0] = *(const float4*)&sW[k][og*8];
            *(float4*)&w[4] = *(const float4*)&sW[k][og*8+4];
#pragma unroll
            for (int i = 0; i < 8; ++i)
#pragma unroll
                for (int j = 0; j < 8; ++j)
                    acc[i][j] += a[i] * w[j];
        }
        __syncthreads();
    }

    float b[8];
#pragma unroll
    for (int j = 0; j < 8; ++j) b[j] = bias[og*8 + j];
#pragma unroll
    for (int i = 0; i < 8; ++i) {
        int n = n0 + ng * 8 + i;
        if (n < N) {
            float4 o0, o1;
            o0.x = fmaxf(acc[i][0] + b[0], 0.f);
            o0.y = fmaxf(acc[i][1] + b[1], 0.f);
            o0.z = fmaxf(acc[i][2] + b[2], 0.f);
            o0.w = fmaxf(acc[i][3] + b[3], 0.f);
            o1.x = fmaxf(acc[i][4] + b[4], 0.f);
            o1.y = fmaxf(acc[i][5] + b[5], 0.f);
            o1.z = fmaxf(acc[i][6] + b[6], 0.f);
            o1.w = fmaxf(acc[i][7] + b[7], 0.f);
            *(float4*)(out + (size_t)n * 128 + og*8)     = o0;
            *(float4*)(out + (size_t)n * 128 + og*8 + 4) = o1;
        }
    }
}

// ------- layer 2: cols 0..63 -> hr = H@Wr^T ; cols 64..127 -> out = H@Wq^T + b2
__global__ __launch_bounds__(256) void gemm2_split(
    const float* __restrict__ H,
    const float* __restrict__ Wr, const float* __restrict__ Wq,
    const float* __restrict__ b2,
    float* __restrict__ hr, float* __restrict__ outp, int N)
{
    __shared__ float sA[KC][LDP];
    __shared__ float sW[KC][LDP];
    const int tid = threadIdx.x;
    const int ng = tid >> 4;
    const int og = tid & 15;
    const int n0 = blockIdx.x * 128;

    float acc[8][8];
#pragma unroll
    for (int i = 0; i < 8; ++i)
#pragma unroll
        for (int j = 0; j < 8; ++j) acc[i][j] = 0.f;

#pragma unroll
    for (int chunk = 0; chunk < 4; ++chunk) {
        const int kc = chunk * KC;
#pragma unroll
        for (int i = 0; i < 4; ++i) {
            int fidx = tid + i * 256;
            int r = fidx >> 3;
            int k4 = fidx & 7;
            int n = n0 + r; if (n >= N) n = N - 1;
            float4 va = *(const float4*)(H + (size_t)n * 128 + kc + k4 * 4);
            sA[k4*4+0][r] = va.x; sA[k4*4+1][r] = va.y;
            sA[k4*4+2][r] = va.z; sA[k4*4+3][r] = va.w;
            const float* wrow = (r < 64) ? (Wr + (size_t)r * 128)
                                         : (Wq + (size_t)(r - 64) * 128);
            float4 vw = *(const float4*)(wrow + kc + k4 * 4);
            sW[k4*4+0][r] = vw.x; sW[k4*4+1][r] = vw.y;
            sW[k4*4+2][r] = vw.z; sW[k4*4+3][r] = vw.w;
        }
        __syncthreads();
#pragma unroll
        for (int k = 0; k < KC; ++k) {
            float a[8], w[8];
            *(float4*)&a[0] = *(const float4*)&sA[k][ng*8];
            *(float4*)&a[4] = *(const float4*)&sA[k][ng*8+4];
            *(float4*)&w[0] = *(const float4*)&sW[k][og*8];
            *(float4*)&w[4] = *(const float4*)&sW[k][og*8+4];
#pragma unroll
            for (int i = 0; i < 8; ++i)
#pragma unroll
                for (int j = 0; j < 8; ++j)
                    acc[i][j] += a[i] * w[j];
        }
        __syncthreads();
    }

    if (og < 8) {
        // rel half -> hr (no bias, scatter adds it to out later)
#pragma unroll
        for (int i = 0; i < 8; ++i) {
            int n = n0 + ng * 8 + i;
            if (n < N) {
                float4 o0 = { acc[i][0], acc[i][1], acc[i][2], acc[i][3] };
                float4 o1 = { acc[i][4], acc[i][5], acc[i][6], acc[i][7] };
                *(float4*)(hr + (size_t)n * 64 + og*8)     = o0;
                *(float4*)(hr + (size_t)n * 64 + og*8 + 4) = o1;
            }
        }
    } else {
        const int oq = (og - 8) * 8;   // column offset in root half
        float b[8];
#pragma unroll
        for (int j = 0; j < 8; ++j) b[j] = b2[oq + j];
#pragma unroll
        for (int i = 0; i < 8; ++i) {
            int n = n0 + ng * 8 + i;
            if (n < N) {
                float4 o0 = { acc[i][0]+b[0], acc[i][1]+b[1], acc[i][2]+b[2], acc[i][3]+b[3] };
                float4 o1 = { acc[i][4]+b[4], acc[i][5]+b[5], acc[i][6]+b[6], acc[i][7]+b[7] };
                *(float4*)(outp + (size_t)n * 64 + oq)     = o0;
                *(float4*)(outp + (size_t)n * 64 + oq + 4) = o1;
            }
        }
    }
}

extern "C" void kernel_launch(void* const* d_in, const int* in_sizes, int n_in,
                              void* d_out, int out_size, void* d_ws, size_t ws_size,
                              hipStream_t stream)
{
    const float* x       = (const float*)d_in[0];
    const int*   ei      = (const int*)d_in[1];
    const float* w_rel1  = (const float*)d_in[2];
    const float* b_rel1  = (const float*)d_in[3];
    const float* w_root1 = (const float*)d_in[4];
    const float* w_rel2  = (const float*)d_in[5];
    const float* b_rel2  = (const float*)d_in[6];
    const float* w_root2 = (const float*)d_in[7];
    float* out = (float*)d_out;

    const int N = in_sizes[0] / 128;
    const int E = in_sizes[1] / 2;
    const int* src = ei;        // edge_index[0]
    const int* dst = ei + E;    // edge_index[1]

    float* agg1 = (float*)d_ws;                  // [N][128]  51.2 MB
    float* h    = agg1 + (size_t)N * 128;        // [N][128]  51.2 MB
    float* hr   = agg1;                          // [N][64] reuse (agg1 dead after gemm1)

    // 1. agg1 = segsum(x[src] -> dst)
    hipMemsetAsync(agg1, 0, (size_t)N * 128 * sizeof(float), stream);
    {
        long total = (long)E * 32;
        int grid = (int)((total + 255) / 256);
        scatter_add_f128<<<grid, 256, 0, stream>>>((const float4*)x, src, dst, agg1, E);
    }
    // 2. h = relu(agg1@Wr1^T + x@Wq1^T + b1)
    {
        int grid = (N + 127) / 128;
        gemm_dual_relu<<<grid, 256, 0, stream>>>(agg1, x, w_rel1, w_root1, b_rel1, h, N);
        // 3. hr = h@Wr2^T ; out = h@Wq2^T + b2
        gemm2_split<<<grid, 256, 0, stream>>>(h, w_rel2, w_root2, b_rel2, hr, out, N);
    }
    // 4. out += segsum(hr[src] -> dst)
    {
        long total = (long)E * 16;
        int grid = (int)((total + 255) / 256);
        scatter_add_f64<<<grid, 256, 0, stream>>>((const float4*)hr, src, dst, out, E);
    }
}

// Round 3
// 4202.219 us; speedup vs baseline: 4.5929x; 4.5929x over previous
//
#include <hip/hip_runtime.h>

// GraphConv x2:
//   agg1 = segsum(x[src]->dst); h = relu(agg1@Wr1^T + x@Wq1^T + b1)
//   hr = h@Wr2^T; out = h@Wq2^T + b2 + segsum(hr[src]->dst)
//
// R2 fix: round-1 GEMMs spilled to scratch (VGPR=256 cap, FETCH 19.5 GB vs
// 0.15 GB algorithmic, VALUBusy 0.46%). Cause: address-taken float[8] frags +
// acc[8][8] under a fully-unrolled chunk loop. Rewritten with ext_vector f4
// (static indexing only) + unroll 1 on the chunk loop.
// (R3 = identical resubmit; R2 bench died to an unresponsive container.)

typedef float f4 __attribute__((ext_vector_type(4)));

#define KC 32
#define LDP 132   // 128 + 4 pad: keeps 16B alignment (132*4=528=33*16), breaks bank stride

__device__ __forceinline__ f4 relu4(f4 v) {
    f4 r;
    r[0] = fmaxf(v[0], 0.f); r[1] = fmaxf(v[1], 0.f);
    r[2] = fmaxf(v[2], 0.f); r[3] = fmaxf(v[3], 0.f);
    return r;
}

// ---------------- edge scatter-add, 128 feats (32 float4/edge) ----------------
__global__ void scatter_add_f128(const float4* __restrict__ x4,
                                 const int* __restrict__ src,
                                 const int* __restrict__ dst,
                                 float* __restrict__ agg, int E)
{
    int t = blockIdx.x * 256 + threadIdx.x;
    int e = t >> 5;
    if (e >= E) return;
    int f = t & 31;
    int s = src[e];
    int d = dst[e];
    float4 v = x4[s * 32 + f];
    float* p = agg + d * 128 + f * 4;
    atomicAdd(p + 0, v.x);
    atomicAdd(p + 1, v.y);
    atomicAdd(p + 2, v.z);
    atomicAdd(p + 3, v.w);
}

// ---------------- edge scatter-add, 64 feats (16 float4/edge) ----------------
__global__ void scatter_add_f64(const float4* __restrict__ h4,
                                const int* __restrict__ src,
                                const int* __restrict__ dst,
                                float* __restrict__ out, int E)
{
    int t = blockIdx.x * 256 + threadIdx.x;
    int e = t >> 4;
    if (e >= E) return;
    int f = t & 15;
    int s = src[e];
    int d = dst[e];
    float4 v = h4[s * 16 + f];
    float* p = out + d * 64 + f * 4;
    atomicAdd(p + 0, v.x);
    atomicAdd(p + 1, v.y);
    atomicAdd(p + 2, v.z);
    atomicAdd(p + 3, v.w);
}

// ------------- layer 1: h = relu(A1@W1^T + A2@W2^T + bias), 128 out ----------
// block: 256 threads, tile 128 nodes x 128 outs, thread = 8 nodes x 8 outs
__global__ __launch_bounds__(256) void gemm_dual_relu(
    const float* __restrict__ A1, const float* __restrict__ A2,
    const float* __restrict__ W1, const float* __restrict__ W2,
    const float* __restrict__ bias, float* __restrict__ out, int N)
{
    __shared__ float sA[KC][LDP];
    __shared__ float sW[KC][LDP];
    const int tid = threadIdx.x;
    const int ng = tid >> 4;   // node group 0..15 (8 nodes each)
    const int og = tid & 15;   // out  group 0..15 (8 outs each)
    const int n0 = blockIdx.x * 128;

    f4 acc[8][2];
#pragma unroll
    for (int i = 0; i < 8; ++i) { acc[i][0] = 0.f; acc[i][1] = 0.f; }

#pragma unroll 1
    for (int chunk = 0; chunk < 8; ++chunk) {
        const float* A = (chunk < 4) ? A1 : A2;
        const float* W = (chunk < 4) ? W1 : W2;
        const int kc = (chunk & 3) * KC;
        // stage A[128n x 32k] -> sA[k][n], W[128o x 32k] -> sW[k][o]
#pragma unroll
        for (int i = 0; i < 4; ++i) {
            int fidx = tid + i * 256;      // float4 index 0..1023
            int r = fidx >> 3;             // row 0..127
            int k4 = fidx & 7;             // which float4 in the 32-k chunk
            int n = n0 + r; if (n >= N) n = N - 1;   // clamp (results masked later)
            f4 va = *(const f4*)(A + (size_t)n * 128 + kc + k4 * 4);
            sA[k4*4+0][r] = va[0]; sA[k4*4+1][r] = va[1];
            sA[k4*4+2][r] = va[2]; sA[k4*4+3][r] = va[3];
            f4 vw = *(const f4*)(W + (size_t)r * 128 + kc + k4 * 4);
            sW[k4*4+0][r] = vw[0]; sW[k4*4+1][r] = vw[1];
            sW[k4*4+2][r] = vw[2]; sW[k4*4+3][r] = vw[3];
        }
        __syncthreads();
#pragma unroll
        for (int k = 0; k < KC; ++k) {
            f4 a0 = *(const f4*)&sA[k][ng*8];
            f4 a1 = *(const f4*)&sA[k][ng*8 + 4];
            f4 w0 = *(const f4*)&sW[k][og*8];
            f4 w1 = *(const f4*)&sW[k][og*8 + 4];
#pragma unroll
            for (int i = 0; i < 4; ++i) {
                acc[i][0]   += a0[i] * w0;
                acc[i][1]   += a0[i] * w1;
                acc[i+4][0] += a1[i] * w0;
                acc[i+4][1] += a1[i] * w1;
            }
        }
        __syncthreads();
    }

    f4 b0 = *(const f4*)(bias + og*8);
    f4 b1 = *(const f4*)(bias + og*8 + 4);
#pragma unroll
    for (int i = 0; i < 8; ++i) {
        int n = n0 + ng * 8 + i;
        if (n < N) {
            *(f4*)(out + (size_t)n * 128 + og*8)     = relu4(acc[i][0] + b0);
            *(f4*)(out + (size_t)n * 128 + og*8 + 4) = relu4(acc[i][1] + b1);
        }
    }
}

// ------- layer 2: cols 0..63 -> hr = H@Wr^T ; cols 64..127 -> out = H@Wq^T + b2
__global__ __launch_bounds__(256) void gemm2_split(
    const float* __restrict__ H,
    const float* __restrict__ Wr, const float* __restrict__ Wq,
    const float* __restrict__ b2,
    float* __restrict__ hr, float* __restrict__ outp, int N)
{
    __shared__ float sA[KC][LDP];
    __shared__ float sW[KC][LDP];
    const int tid = threadIdx.x;
    const int ng = tid >> 4;
    const int og = tid & 15;
    const int n0 = blockIdx.x * 128;

    f4 acc[8][2];
#pragma unroll
    for (int i = 0; i < 8; ++i) { acc[i][0] = 0.f; acc[i][1] = 0.f; }

#pragma unroll 1
    for (int chunk = 0; chunk < 4; ++chunk) {
        const int kc = chunk * KC;
#pragma unroll
        for (int i = 0; i < 4; ++i) {
            int fidx = tid + i * 256;
            int r = fidx >> 3;
            int k4 = fidx & 7;
            int n = n0 + r; if (n >= N) n = N - 1;
            f4 va = *(const f4*)(H + (size_t)n * 128 + kc + k4 * 4);
            sA[k4*4+0][r] = va[0]; sA[k4*4+1][r] = va[1];
            sA[k4*4+2][r] = va[2]; sA[k4*4+3][r] = va[3];
            const float* wrow = (r < 64) ? (Wr + (size_t)r * 128)
                                         : (Wq + (size_t)(r - 64) * 128);
            f4 vw = *(const f4*)(wrow + kc + k4 * 4);
            sW[k4*4+0][r] = vw[0]; sW[k4*4+1][r] = vw[1];
            sW[k4*4+2][r] = vw[2]; sW[k4*4+3][r] = vw[3];
        }
        __syncthreads();
#pragma unroll
        for (int k = 0; k < KC; ++k) {
            f4 a0 = *(const f4*)&sA[k][ng*8];
            f4 a1 = *(const f4*)&sA[k][ng*8 + 4];
            f4 w0 = *(const f4*)&sW[k][og*8];
            f4 w1 = *(const f4*)&sW[k][og*8 + 4];
#pragma unroll
            for (int i = 0; i < 4; ++i) {
                acc[i][0]   += a0[i] * w0;
                acc[i][1]   += a0[i] * w1;
                acc[i+4][0] += a1[i] * w0;
                acc[i+4][1] += a1[i] * w1;
            }
        }
        __syncthreads();
    }

    if (og < 8) {
        // rel half -> hr (no bias, scatter adds it to out later)
#pragma unroll
        for (int i = 0; i < 8; ++i) {
            int n = n0 + ng * 8 + i;
            if (n < N) {
                *(f4*)(hr + (size_t)n * 64 + og*8)     = acc[i][0];
                *(f4*)(hr + (size_t)n * 64 + og*8 + 4) = acc[i][1];
            }
        }
    } else {
        const int oq = (og - 8) * 8;   // column offset in root half
        f4 b0 = *(const f4*)(b2 + oq);
        f4 b1 = *(const f4*)(b2 + oq + 4);
#pragma unroll
        for (int i = 0; i < 8; ++i) {
            int n = n0 + ng * 8 + i;
            if (n < N) {
                *(f4*)(outp + (size_t)n * 64 + oq)     = acc[i][0] + b0;
                *(f4*)(outp + (size_t)n * 64 + oq + 4) = acc[i][1] + b1;
            }
        }
    }
}

extern "C" void kernel_launch(void* const* d_in, const int* in_sizes, int n_in,
                              void* d_out, int out_size, void* d_ws, size_t ws_size,
                              hipStream_t stream)
{
    const float* x       = (const float*)d_in[0];
    const int*   ei      = (const int*)d_in[1];
    const float* w_rel1  = (const float*)d_in[2];
    const float* b_rel1  = (const float*)d_in[3];
    const float* w_root1 = (const float*)d_in[4];
    const float* w_rel2  = (const float*)d_in[5];
    const float* b_rel2  = (const float*)d_in[6];
    const float* w_root2 = (const float*)d_in[7];
    float* out = (float*)d_out;

    const int N = in_sizes[0] / 128;
    const int E = in_sizes[1] / 2;
    const int* src = ei;        // edge_index[0]
    const int* dst = ei + E;    // edge_index[1]

    float* agg1 = (float*)d_ws;                  // [N][128]  51.2 MB
    float* h    = agg1 + (size_t)N * 128;        // [N][128]  51.2 MB
    float* hr   = agg1;                          // [N][64] reuse (agg1 dead after gemm1)

    // 1. agg1 = segsum(x[src] -> dst)
    hipMemsetAsync(agg1, 0, (size_t)N * 128 * sizeof(float), stream);
    {
        long total = (long)E * 32;
        int grid = (int)((total + 255) / 256);
        scatter_add_f128<<<grid, 256, 0, stream>>>((const float4*)x, src, dst, agg1, E);
    }
    // 2. h = relu(agg1@Wr1^T + x@Wq1^T + b1)
    {
        int grid = (N + 127) / 128;
        gemm_dual_relu<<<grid, 256, 0, stream>>>(agg1, x, w_rel1, w_root1, b_rel1, h, N);
        // 3. hr = h@Wr2^T ; out = h@Wq2^T + b2
        gemm2_split<<<grid, 256, 0, stream>>>(h, w_rel2, w_root2, b_rel2, hr, out, N);
    }
    // 4. out += segsum(hr[src] -> dst)
    {
        long total = (long)E * 16;
        int grid = (int)((total + 255) / 256);
        scatter_add_f64<<<grid, 256, 0, stream>>>((const float4*)hr, src, dst, out, E);
    }
}

// Round 4
// 726.769 us; speedup vs baseline: 26.5564x; 5.7821x over previous
//
#include <hip/hip_runtime.h>

// GraphConv x2, CSR-pull version:
//   CSR build (hist -> scan -> fill), reused by BOTH layers
//   agg1[n] = sum_{j in N(n)} x[src_j]          (pull, no atomics)
//   h = relu(agg1@Wr1^T + x@Wq1^T + b1)         (in-place over agg1)
//   hr = h@Wr2^T ; out = h@Wq2^T + b2
//   out[n] += sum_{j in N(n)} hr[src_j]         (pull, no atomics)
//
// R4: round-3 profile showed scatter_add_f128 = 2.68 ms (VALUBusy 0.8%,
// WRITE_SIZE 3.2 GB for a 51 MB dest -> L2 atomic thrash). CSR-pull removes
// all 307M f32 atomics; CSR build costs only 3.2M int atomics, amortized
// over both layers.

typedef float f4 __attribute__((ext_vector_type(4)));

#define KC 32
#define LDP 132   // 128 + 4 pad: keeps 16B alignment (132*4=528=33*16), breaks bank stride

__device__ __forceinline__ f4 relu4(f4 v) {
    f4 r;
    r[0] = fmaxf(v[0], 0.f); r[1] = fmaxf(v[1], 0.f);
    r[2] = fmaxf(v[2], 0.f); r[3] = fmaxf(v[3], 0.f);
    return r;
}

// ---------------------------- CSR build ------------------------------------
__global__ void hist_dst(const int* __restrict__ dst, int* __restrict__ cnt, int E)
{
    int e = blockIdx.x * 256 + threadIdx.x;
    if (e < E) atomicAdd(&cnt[dst[e]], 1);
}

// single-block exclusive scan over N counts -> row_ptr[0..N]
__global__ __launch_bounds__(1024) void scan_rowptr(const int* __restrict__ cnt,
                                                    int* __restrict__ row_ptr, int N)
{
    __shared__ int ts[1024];
    const int tid = threadIdx.x;
    const int per = (N + 1023) >> 10;
    const int lo = tid * per;
    const int hi = min(lo + per, N);
    int s = 0;
    for (int i = lo; i < hi; ++i) s += cnt[i];
    ts[tid] = s;
    __syncthreads();
    for (int off = 1; off < 1024; off <<= 1) {
        int add = (tid >= off) ? ts[tid - off] : 0;
        __syncthreads();
        ts[tid] += add;
        __syncthreads();
    }
    int run = (tid > 0) ? ts[tid - 1] : 0;
    for (int i = lo; i < hi; ++i) { row_ptr[i] = run; run += cnt[i]; }
    if (tid == 1023) row_ptr[N] = ts[1023];
}

// cur[] starts as a copy of row_ptr[0..N); bucket edges by dst, storing src
__global__ void fill_csr(const int* __restrict__ src, const int* __restrict__ dst,
                         int* __restrict__ cur, int* __restrict__ srcs, int E)
{
    int e = blockIdx.x * 256 + threadIdx.x;
    if (e < E) {
        int p = atomicAdd(&cur[dst[e]], 1);
        srcs[p] = src[e];
    }
}

// --------------------------- pull kernels ----------------------------------
// one wave per node; lane handles 2 feats (128 feats = 64 lanes x float2)
__global__ __launch_bounds__(256) void pull_f128(const float* __restrict__ x,
                                                 const int* __restrict__ row_ptr,
                                                 const int* __restrict__ srcs,
                                                 float* __restrict__ agg, int N)
{
    int w = (blockIdx.x * 256 + threadIdx.x) >> 6;
    int lane = threadIdx.x & 63;
    if (w >= N) return;
    const int beg = row_ptr[w], end = row_ptr[w + 1];
    const float2* x2 = (const float2*)x;
    float ax = 0.f, ay = 0.f;
    int j = beg;
    for (; j + 1 < end; j += 2) {            // 2-edge unroll for MLP
        int s0 = srcs[j], s1 = srcs[j + 1];
        float2 v0 = x2[(size_t)s0 * 64 + lane];
        float2 v1 = x2[(size_t)s1 * 64 + lane];
        ax += v0.x + v1.x; ay += v0.y + v1.y;
    }
    if (j < end) {
        int s0 = srcs[j];
        float2 v0 = x2[(size_t)s0 * 64 + lane];
        ax += v0.x; ay += v0.y;
    }
    float2 o; o.x = ax; o.y = ay;
    ((float2*)agg)[(size_t)w * 64 + lane] = o;
}

// one wave per node; lane handles 1 feat (64 feats); out += pulled sum
__global__ __launch_bounds__(256) void pull_add_f64(const float* __restrict__ hr,
                                                    const int* __restrict__ row_ptr,
                                                    const int* __restrict__ srcs,
                                                    float* __restrict__ out, int N)
{
    int w = (blockIdx.x * 256 + threadIdx.x) >> 6;
    int lane = threadIdx.x & 63;
    if (w >= N) return;
    const int beg = row_ptr[w], end = row_ptr[w + 1];
    float acc = 0.f;
    int j = beg;
    for (; j + 1 < end; j += 2) {
        int s0 = srcs[j], s1 = srcs[j + 1];
        acc += hr[(size_t)s0 * 64 + lane] + hr[(size_t)s1 * 64 + lane];
    }
    if (j < end) acc += hr[(size_t)srcs[j] * 64 + lane];
    out[(size_t)w * 64 + lane] += acc;
}

// ------------- layer 1: h = relu(A1@W1^T + A2@W2^T + bias), 128 out ----------
// block: 256 threads, tile 128 nodes x 128 outs, thread = 8 nodes x 8 outs.
// Safe to call with out == A1 (each block writes only rows it alone reads,
// and all A1 reads complete before the epilogue writes).
__global__ __launch_bounds__(256) void gemm_dual_relu(
    const float* __restrict__ A1, const float* __restrict__ A2,
    const float* __restrict__ W1, const float* __restrict__ W2,
    const float* __restrict__ bias, float* __restrict__ out, int N)
{
    __shared__ float sA[KC][LDP];
    __shared__ float sW[KC][LDP];
    const int tid = threadIdx.x;
    const int ng = tid >> 4;   // node group 0..15 (8 nodes each)
    const int og = tid & 15;   // out  group 0..15 (8 outs each)
    const int n0 = blockIdx.x * 128;

    f4 acc[8][2];
#pragma unroll
    for (int i = 0; i < 8; ++i) { acc[i][0] = 0.f; acc[i][1] = 0.f; }

#pragma unroll 1
    for (int chunk = 0; chunk < 8; ++chunk) {
        const float* A = (chunk < 4) ? A1 : A2;
        const float* W = (chunk < 4) ? W1 : W2;
        const int kc = (chunk & 3) * KC;
        // stage A[128n x 32k] -> sA[k][n], W[128o x 32k] -> sW[k][o]
#pragma unroll
        for (int i = 0; i < 4; ++i) {
            int fidx = tid + i * 256;      // float4 index 0..1023
            int r = fidx >> 3;             // row 0..127
            int k4 = fidx & 7;             // which float4 in the 32-k chunk
            int n = n0 + r; if (n >= N) n = N - 1;   // clamp (results masked later)
            f4 va = *(const f4*)(A + (size_t)n * 128 + kc + k4 * 4);
            sA[k4*4+0][r] = va[0]; sA[k4*4+1][r] = va[1];
            sA[k4*4+2][r] = va[2]; sA[k4*4+3][r] = va[3];
            f4 vw = *(const f4*)(W + (size_t)r * 128 + kc + k4 * 4);
            sW[k4*4+0][r] = vw[0]; sW[k4*4+1][r] = vw[1];
            sW[k4*4+2][r] = vw[2]; sW[k4*4+3][r] = vw[3];
        }
        __syncthreads();
#pragma unroll
        for (int k = 0; k < KC; ++k) {
            f4 a0 = *(const f4*)&sA[k][ng*8];
            f4 a1 = *(const f4*)&sA[k][ng*8 + 4];
            f4 w0 = *(const f4*)&sW[k][og*8];
            f4 w1 = *(const f4*)&sW[k][og*8 + 4];
#pragma unroll
            for (int i = 0; i < 4; ++i) {
                acc[i][0]   += a0[i] * w0;
                acc[i][1]   += a0[i] * w1;
                acc[i+4][0] += a1[i] * w0;
                acc[i+4][1] += a1[i] * w1;
            }
        }
        __syncthreads();
    }

    f4 b0 = *(const f4*)(bias + og*8);
    f4 b1 = *(const f4*)(bias + og*8 + 4);
#pragma unroll
    for (int i = 0; i < 8; ++i) {
        int n = n0 + ng * 8 + i;
        if (n < N) {
            *(f4*)(out + (size_t)n * 128 + og*8)     = relu4(acc[i][0] + b0);
            *(f4*)(out + (size_t)n * 128 + og*8 + 4) = relu4(acc[i][1] + b1);
        }
    }
}

// ------- layer 2: cols 0..63 -> hr = H@Wr^T ; cols 64..127 -> out = H@Wq^T + b2
__global__ __launch_bounds__(256) void gemm2_split(
    const float* __restrict__ H,
    const float* __restrict__ Wr, const float* __restrict__ Wq,
    const float* __restrict__ b2,
    float* __restrict__ hr, float* __restrict__ outp, int N)
{
    __shared__ float sA[KC][LDP];
    __shared__ float sW[KC][LDP];
    const int tid = threadIdx.x;
    const int ng = tid >> 4;
    const int og = tid & 15;
    const int n0 = blockIdx.x * 128;

    f4 acc[8][2];
#pragma unroll
    for (int i = 0; i < 8; ++i) { acc[i][0] = 0.f; acc[i][1] = 0.f; }

#pragma unroll 1
    for (int chunk = 0; chunk < 4; ++chunk) {
        const int kc = chunk * KC;
#pragma unroll
        for (int i = 0; i < 4; ++i) {
            int fidx = tid + i * 256;
            int r = fidx >> 3;
            int k4 = fidx & 7;
            int n = n0 + r; if (n >= N) n = N - 1;
            f4 va = *(const f4*)(H + (size_t)n * 128 + kc + k4 * 4);
            sA[k4*4+0][r] = va[0]; sA[k4*4+1][r] = va[1];
            sA[k4*4+2][r] = va[2]; sA[k4*4+3][r] = va[3];
            const float* wrow = (r < 64) ? (Wr + (size_t)r * 128)
                                         : (Wq + (size_t)(r - 64) * 128);
            f4 vw = *(const f4*)(wrow + kc + k4 * 4);
            sW[k4*4+0][r] = vw[0]; sW[k4*4+1][r] = vw[1];
            sW[k4*4+2][r] = vw[2]; sW[k4*4+3][r] = vw[3];
        }
        __syncthreads();
#pragma unroll
        for (int k = 0; k < KC; ++k) {
            f4 a0 = *(const f4*)&sA[k][ng*8];
            f4 a1 = *(const f4*)&sA[k][ng*8 + 4];
            f4 w0 = *(const f4*)&sW[k][og*8];
            f4 w1 = *(const f4*)&sW[k][og*8 + 4];
#pragma unroll
            for (int i = 0; i < 4; ++i) {
                acc[i][0]   += a0[i] * w0;
                acc[i][1]   += a0[i] * w1;
                acc[i+4][0] += a1[i] * w0;
                acc[i+4][1] += a1[i] * w1;
            }
        }
        __syncthreads();
    }

    if (og < 8) {
        // rel half -> hr (no bias; pull_add adds it into out later)
#pragma unroll
        for (int i = 0; i < 8; ++i) {
            int n = n0 + ng * 8 + i;
            if (n < N) {
                *(f4*)(hr + (size_t)n * 64 + og*8)     = acc[i][0];
                *(f4*)(hr + (size_t)n * 64 + og*8 + 4) = acc[i][1];
            }
        }
    } else {
        const int oq = (og - 8) * 8;   // column offset in root half
        f4 b0 = *(const f4*)(b2 + oq);
        f4 b1 = *(const f4*)(b2 + oq + 4);
#pragma unroll
        for (int i = 0; i < 8; ++i) {
            int n = n0 + ng * 8 + i;
            if (n < N) {
                *(f4*)(outp + (size_t)n * 64 + oq)     = acc[i][0] + b0;
                *(f4*)(outp + (size_t)n * 64 + oq + 4) = acc[i][1] + b1;
            }
        }
    }
}

extern "C" void kernel_launch(void* const* d_in, const int* in_sizes, int n_in,
                              void* d_out, int out_size, void* d_ws, size_t ws_size,
                              hipStream_t stream)
{
    const float* x       = (const float*)d_in[0];
    const int*   ei      = (const int*)d_in[1];
    const float* w_rel1  = (const float*)d_in[2];
    const float* b_rel1  = (const float*)d_in[3];
    const float* w_root1 = (const float*)d_in[4];
    const float* w_rel2  = (const float*)d_in[5];
    const float* b_rel2  = (const float*)d_in[6];
    const float* w_root2 = (const float*)d_in[7];
    float* out = (float*)d_out;

    const int N = in_sizes[0] / 128;
    const int E = in_sizes[1] / 2;
    const int* src = ei;        // edge_index[0]
    const int* dst = ei + E;    // edge_index[1]

    // workspace layout (~84 MB): agg1/h [N][128] | hr [N][64] | row_ptr | cnt | srcs
    float* agg1   = (float*)d_ws;                    // N*128 f32 (h written in-place)
    float* hr     = agg1 + (size_t)N * 128;          // N*64 f32
    int*   row_ptr = (int*)(hr + (size_t)N * 64);    // N+1
    int*   cnt     = row_ptr + (N + 1);              // N (reused as fill cursor)
    int*   srcs    = cnt + N;                        // E

    // ---- CSR build (shared by both layers) ----
    hipMemsetAsync(cnt, 0, (size_t)N * sizeof(int), stream);
    {
        int grid = (E + 255) / 256;
        hist_dst<<<grid, 256, 0, stream>>>(dst, cnt, E);
    }
    scan_rowptr<<<1, 1024, 0, stream>>>(cnt, row_ptr, N);
    hipMemcpyAsync(cnt, row_ptr, (size_t)N * sizeof(int),
                   hipMemcpyDeviceToDevice, stream);      // cursor = row_ptr copy
    {
        int grid = (E + 255) / 256;
        fill_csr<<<grid, 256, 0, stream>>>(src, dst, cnt, srcs, E);
    }

    const int pull_grid = (N * 64 + 255) / 256;   // one wave per node
    // 1. agg1 = pull-sum x
    pull_f128<<<pull_grid, 256, 0, stream>>>(x, row_ptr, srcs, agg1, N);
    // 2. h = relu(agg1@Wr1^T + x@Wq1^T + b1)   (in-place: h == agg1)
    {
        int grid = (N + 127) / 128;
        gemm_dual_relu<<<grid, 256, 0, stream>>>(agg1, x, w_rel1, w_root1, b_rel1, agg1, N);
        // 3. hr = h@Wr2^T ; out = h@Wq2^T + b2
        gemm2_split<<<grid, 256, 0, stream>>>(agg1, w_rel2, w_root2, b_rel2, hr, out, N);
    }
    // 4. out += pull-sum hr
    pull_add_f64<<<pull_grid, 256, 0, stream>>>(hr, row_ptr, srcs, out, N);
}

// Round 5
// 545.260 us; speedup vs baseline: 35.3966x; 1.3329x over previous
//
#include <hip/hip_runtime.h>

// GraphConv x2, CSR-pull version:
//   CSR build (hist -> 3-phase scan -> fill), reused by BOTH layers
//   agg1[n] = sum_{j in N(n)} x[src_j]          (pull, no atomics)
//   h = relu(agg1@Wr1^T + x@Wq1^T + b1)         (in-place over agg1)
//   hr = h@Wr2^T ; out = h@Wq2^T + b2
//   out[n] += sum_{j in N(n)} hr[src_j]         (pull, no atomics)
//
// R5: round-4 profile showed scan_rowptr = 164 µs at 0.16% occupancy (one
// 1024-thread block on one CU, latency-bound). Replaced with a device-wide
// 3-phase scan (~15 µs) whose phase 3 also initializes the fill cursor,
// removing the 400 KB D2D memcpy. Pull kernels: edge unroll 2 -> 4.

typedef float f4 __attribute__((ext_vector_type(4)));

#define KC 32
#define LDP 132   // 128 + 4 pad: keeps 16B alignment (132*4=528=33*16), breaks bank stride

__device__ __forceinline__ f4 relu4(f4 v) {
    f4 r;
    r[0] = fmaxf(v[0], 0.f); r[1] = fmaxf(v[1], 0.f);
    r[2] = fmaxf(v[2], 0.f); r[3] = fmaxf(v[3], 0.f);
    return r;
}

// ---------------------------- CSR build ------------------------------------
__global__ void hist_dst(const int* __restrict__ dst, int* __restrict__ cnt, int E)
{
    int e = blockIdx.x * 256 + threadIdx.x;
    if (e < E) atomicAdd(&cnt[dst[e]], 1);
}

// phase 1: per-256-tile scan; row_ptr[i] = tile-local exclusive prefix,
// blk_sum[b] = tile total
__global__ __launch_bounds__(256) void scan_p1(const int* __restrict__ cnt,
                                               int* __restrict__ row_ptr,
                                               int* __restrict__ blk_sum, int N)
{
    __shared__ int ts[256];
    const int tid = threadIdx.x;
    const int i = blockIdx.x * 256 + tid;
    int v = (i < N) ? cnt[i] : 0;
    ts[tid] = v;
    __syncthreads();
#pragma unroll
    for (int off = 1; off < 256; off <<= 1) {
        int add = (tid >= off) ? ts[tid - off] : 0;
        __syncthreads();
        ts[tid] += add;
        __syncthreads();
    }
    if (i < N) row_ptr[i] = ts[tid] - v;          // exclusive within tile
    if (tid == 255) blk_sum[blockIdx.x] = ts[255];
}

// phase 2: single block, exclusive scan over nb block sums (nb <= 1024)
__global__ __launch_bounds__(1024) void scan_p2(int* __restrict__ blk_sum, int nb)
{
    __shared__ int ts[1024];
    const int tid = threadIdx.x;
    int v = (tid < nb) ? blk_sum[tid] : 0;
    ts[tid] = v;
    __syncthreads();
#pragma unroll
    for (int off = 1; off < 1024; off <<= 1) {
        int add = (tid >= off) ? ts[tid - off] : 0;
        __syncthreads();
        ts[tid] += add;
        __syncthreads();
    }
    if (tid < nb) blk_sum[tid] = ts[tid] - v;     // exclusive
}

// phase 3: add block offset; write final row_ptr AND the fill cursor copy
__global__ __launch_bounds__(256) void scan_p3(int* __restrict__ row_ptr,
                                               const int* __restrict__ blk_sum,
                                               int* __restrict__ cur, int N, int E)
{
    const int i = blockIdx.x * 256 + threadIdx.x;
    if (i < N) {
        int v = row_ptr[i] + blk_sum[blockIdx.x];
        row_ptr[i] = v;
        cur[i] = v;
    }
    if (i == 0) row_ptr[N] = E;
}

// cur[] starts as a copy of row_ptr[0..N); bucket edges by dst, storing src
__global__ void fill_csr(const int* __restrict__ src, const int* __restrict__ dst,
                         int* __restrict__ cur, int* __restrict__ srcs, int E)
{
    int e = blockIdx.x * 256 + threadIdx.x;
    if (e < E) {
        int p = atomicAdd(&cur[dst[e]], 1);
        srcs[p] = src[e];
    }
}

// --------------------------- pull kernels ----------------------------------
// one wave per node; lane handles 2 feats (128 feats = 64 lanes x float2)
__global__ __launch_bounds__(256) void pull_f128(const float* __restrict__ x,
                                                 const int* __restrict__ row_ptr,
                                                 const int* __restrict__ srcs,
                                                 float* __restrict__ agg, int N)
{
    int w = (blockIdx.x * 256 + threadIdx.x) >> 6;
    int lane = threadIdx.x & 63;
    if (w >= N) return;
    const int beg = row_ptr[w], end = row_ptr[w + 1];
    const float2* x2 = (const float2*)x;
    float ax = 0.f, ay = 0.f;
    int j = beg;
    for (; j + 3 < end; j += 4) {            // 4-edge unroll for MLP
        int s0 = srcs[j], s1 = srcs[j + 1], s2 = srcs[j + 2], s3 = srcs[j + 3];
        float2 v0 = x2[(size_t)s0 * 64 + lane];
        float2 v1 = x2[(size_t)s1 * 64 + lane];
        float2 v2 = x2[(size_t)s2 * 64 + lane];
        float2 v3 = x2[(size_t)s3 * 64 + lane];
        ax += (v0.x + v1.x) + (v2.x + v3.x);
        ay += (v0.y + v1.y) + (v2.y + v3.y);
    }
    for (; j < end; ++j) {
        float2 v0 = x2[(size_t)srcs[j] * 64 + lane];
        ax += v0.x; ay += v0.y;
    }
    float2 o; o.x = ax; o.y = ay;
    ((float2*)agg)[(size_t)w * 64 + lane] = o;
}

// one wave per node; lane handles 1 feat (64 feats); out += pulled sum
__global__ __launch_bounds__(256) void pull_add_f64(const float* __restrict__ hr,
                                                    const int* __restrict__ row_ptr,
                                                    const int* __restrict__ srcs,
                                                    float* __restrict__ out, int N)
{
    int w = (blockIdx.x * 256 + threadIdx.x) >> 6;
    int lane = threadIdx.x & 63;
    if (w >= N) return;
    const int beg = row_ptr[w], end = row_ptr[w + 1];
    float acc = 0.f;
    int j = beg;
    for (; j + 3 < end; j += 4) {
        int s0 = srcs[j], s1 = srcs[j + 1], s2 = srcs[j + 2], s3 = srcs[j + 3];
        acc += (hr[(size_t)s0 * 64 + lane] + hr[(size_t)s1 * 64 + lane])
             + (hr[(size_t)s2 * 64 + lane] + hr[(size_t)s3 * 64 + lane]);
    }
    for (; j < end; ++j) acc += hr[(size_t)srcs[j] * 64 + lane];
    out[(size_t)w * 64 + lane] += acc;
}

// ------------- layer 1: h = relu(A1@W1^T + A2@W2^T + bias), 128 out ----------
// block: 256 threads, tile 128 nodes x 128 outs, thread = 8 nodes x 8 outs.
// Safe to call with out == A1 (each block writes only rows it alone reads,
// and all A1 reads complete before the epilogue writes).
__global__ __launch_bounds__(256) void gemm_dual_relu(
    const float* __restrict__ A1, const float* __restrict__ A2,
    const float* __restrict__ W1, const float* __restrict__ W2,
    const float* __restrict__ bias, float* __restrict__ out, int N)
{
    __shared__ float sA[KC][LDP];
    __shared__ float sW[KC][LDP];
    const int tid = threadIdx.x;
    const int ng = tid >> 4;   // node group 0..15 (8 nodes each)
    const int og = tid & 15;   // out  group 0..15 (8 outs each)
    const int n0 = blockIdx.x * 128;

    f4 acc[8][2];
#pragma unroll
    for (int i = 0; i < 8; ++i) { acc[i][0] = 0.f; acc[i][1] = 0.f; }

#pragma unroll 1
    for (int chunk = 0; chunk < 8; ++chunk) {
        const float* A = (chunk < 4) ? A1 : A2;
        const float* W = (chunk < 4) ? W1 : W2;
        const int kc = (chunk & 3) * KC;
        // stage A[128n x 32k] -> sA[k][n], W[128o x 32k] -> sW[k][o]
#pragma unroll
        for (int i = 0; i < 4; ++i) {
            int fidx = tid + i * 256;      // float4 index 0..1023
            int r = fidx >> 3;             // row 0..127
            int k4 = fidx & 7;             // which float4 in the 32-k chunk
            int n = n0 + r; if (n >= N) n = N - 1;   // clamp (results masked later)
            f4 va = *(const f4*)(A + (size_t)n * 128 + kc + k4 * 4);
            sA[k4*4+0][r] = va[0]; sA[k4*4+1][r] = va[1];
            sA[k4*4+2][r] = va[2]; sA[k4*4+3][r] = va[3];
            f4 vw = *(const f4*)(W + (size_t)r * 128 + kc + k4 * 4);
            sW[k4*4+0][r] = vw[0]; sW[k4*4+1][r] = vw[1];
            sW[k4*4+2][r] = vw[2]; sW[k4*4+3][r] = vw[3];
        }
        __syncthreads();
#pragma unroll
        for (int k = 0; k < KC; ++k) {
            f4 a0 = *(const f4*)&sA[k][ng*8];
            f4 a1 = *(const f4*)&sA[k][ng*8 + 4];
            f4 w0 = *(const f4*)&sW[k][og*8];
            f4 w1 = *(const f4*)&sW[k][og*8 + 4];
#pragma unroll
            for (int i = 0; i < 4; ++i) {
                acc[i][0]   += a0[i] * w0;
                acc[i][1]   += a0[i] * w1;
                acc[i+4][0] += a1[i] * w0;
                acc[i+4][1] += a1[i] * w1;
            }
        }
        __syncthreads();
    }

    f4 b0 = *(const f4*)(bias + og*8);
    f4 b1 = *(const f4*)(bias + og*8 + 4);
#pragma unroll
    for (int i = 0; i < 8; ++i) {
        int n = n0 + ng * 8 + i;
        if (n < N) {
            *(f4*)(out + (size_t)n * 128 + og*8)     = relu4(acc[i][0] + b0);
            *(f4*)(out + (size_t)n * 128 + og*8 + 4) = relu4(acc[i][1] + b1);
        }
    }
}

// ------- layer 2: cols 0..63 -> hr = H@Wr^T ; cols 64..127 -> out = H@Wq^T + b2
__global__ __launch_bounds__(256) void gemm2_split(
    const float* __restrict__ H,
    const float* __restrict__ Wr, const float* __restrict__ Wq,
    const float* __restrict__ b2,
    float* __restrict__ hr, float* __restrict__ outp, int N)
{
    __shared__ float sA[KC][LDP];
    __shared__ float sW[KC][LDP];
    const int tid = threadIdx.x;
    const int ng = tid >> 4;
    const int og = tid & 15;
    const int n0 = blockIdx.x * 128;

    f4 acc[8][2];
#pragma unroll
    for (int i = 0; i < 8; ++i) { acc[i][0] = 0.f; acc[i][1] = 0.f; }

#pragma unroll 1
    for (int chunk = 0; chunk < 4; ++chunk) {
        const int kc = chunk * KC;
#pragma unroll
        for (int i = 0; i < 4; ++i) {
            int fidx = tid + i * 256;
            int r = fidx >> 3;
            int k4 = fidx & 7;
            int n = n0 + r; if (n >= N) n = N - 1;
            f4 va = *(const f4*)(H + (size_t)n * 128 + kc + k4 * 4);
            sA[k4*4+0][r] = va[0]; sA[k4*4+1][r] = va[1];
            sA[k4*4+2][r] = va[2]; sA[k4*4+3][r] = va[3];
            const float* wrow = (r < 64) ? (Wr + (size_t)r * 128)
                                         : (Wq + (size_t)(r - 64) * 128);
            f4 vw = *(const f4*)(wrow + kc + k4 * 4);
            sW[k4*4+0][r] = vw[0]; sW[k4*4+1][r] = vw[1];
            sW[k4*4+2][r] = vw[2]; sW[k4*4+3][r] = vw[3];
        }
        __syncthreads();
#pragma unroll
        for (int k = 0; k < KC; ++k) {
            f4 a0 = *(const f4*)&sA[k][ng*8];
            f4 a1 = *(const f4*)&sA[k][ng*8 + 4];
            f4 w0 = *(const f4*)&sW[k][og*8];
            f4 w1 = *(const f4*)&sW[k][og*8 + 4];
#pragma unroll
            for (int i = 0; i < 4; ++i) {
                acc[i][0]   += a0[i] * w0;
                acc[i][1]   += a0[i] * w1;
                acc[i+4][0] += a1[i] * w0;
                acc[i+4][1] += a1[i] * w1;
            }
        }
        __syncthreads();
    }

    if (og < 8) {
        // rel half -> hr (no bias; pull_add adds it into out later)
#pragma unroll
        for (int i = 0; i < 8; ++i) {
            int n = n0 + ng * 8 + i;
            if (n < N) {
                *(f4*)(hr + (size_t)n * 64 + og*8)     = acc[i][0];
                *(f4*)(hr + (size_t)n * 64 + og*8 + 4) = acc[i][1];
            }
        }
    } else {
        const int oq = (og - 8) * 8;   // column offset in root half
        f4 b0 = *(const f4*)(b2 + oq);
        f4 b1 = *(const f4*)(b2 + oq + 4);
#pragma unroll
        for (int i = 0; i < 8; ++i) {
            int n = n0 + ng * 8 + i;
            if (n < N) {
                *(f4*)(outp + (size_t)n * 64 + oq)     = acc[i][0] + b0;
                *(f4*)(outp + (size_t)n * 64 + oq + 4) = acc[i][1] + b1;
            }
        }
    }
}

extern "C" void kernel_launch(void* const* d_in, const int* in_sizes, int n_in,
                              void* d_out, int out_size, void* d_ws, size_t ws_size,
                              hipStream_t stream)
{
    const float* x       = (const float*)d_in[0];
    const int*   ei      = (const int*)d_in[1];
    const float* w_rel1  = (const float*)d_in[2];
    const float* b_rel1  = (const float*)d_in[3];
    const float* w_root1 = (const float*)d_in[4];
    const float* w_rel2  = (const float*)d_in[5];
    const float* b_rel2  = (const float*)d_in[6];
    const float* w_root2 = (const float*)d_in[7];
    float* out = (float*)d_out;

    const int N = in_sizes[0] / 128;
    const int E = in_sizes[1] / 2;
    const int* src = ei;        // edge_index[0]
    const int* dst = ei + E;    // edge_index[1]

    // workspace (~84 MB): agg1/h [N][128] | hr [N][64] | row_ptr | cnt | srcs | blk_sum
    float* agg1    = (float*)d_ws;                   // N*128 f32 (h written in-place)
    float* hr      = agg1 + (size_t)N * 128;         // N*64 f32
    int*   row_ptr = (int*)(hr + (size_t)N * 64);    // N+1
    int*   cnt     = row_ptr + (N + 1);              // N (reused as fill cursor)
    int*   srcs    = cnt + N;                        // E
    int*   blk_sum = srcs + E;                       // <=1024

    const int nb = (N + 255) / 256;                  // scan tiles (N<=262144)

    // ---- CSR build (shared by both layers) ----
    hipMemsetAsync(cnt, 0, (size_t)N * sizeof(int), stream);
    {
        int grid = (E + 255) / 256;
        hist_dst<<<grid, 256, 0, stream>>>(dst, cnt, E);
    }
    scan_p1<<<nb, 256, 0, stream>>>(cnt, row_ptr, blk_sum, N);
    scan_p2<<<1, 1024, 0, stream>>>(blk_sum, nb);
    scan_p3<<<nb, 256, 0, stream>>>(row_ptr, blk_sum, cnt, N, E);
    {
        int grid = (E + 255) / 256;
        fill_csr<<<grid, 256, 0, stream>>>(src, dst, cnt, srcs, E);
    }

    const int pull_grid = (N * 64 + 255) / 256;   // one wave per node
    // 1. agg1 = pull-sum x
    pull_f128<<<pull_grid, 256, 0, stream>>>(x, row_ptr, srcs, agg1, N);
    // 2. h = relu(agg1@Wr1^T + x@Wq1^T + b1)   (in-place: h == agg1)
    {
        int grid = (N + 127) / 128;
        gemm_dual_relu<<<grid, 256, 0, stream>>>(agg1, x, w_rel1, w_root1, b_rel1, agg1, N);
        // 3. hr = h@Wr2^T ; out = h@Wq2^T + b2
        gemm2_split<<<grid, 256, 0, stream>>>(agg1, w_rel2, w_root2, b_rel2, hr, out, N);
    }
    // 4. out += pull-sum hr
    pull_add_f64<<<pull_grid, 256, 0, stream>>>(hr, row_ptr, srcs, out, N);
}

// Round 6
// 378.006 us; speedup vs baseline: 51.0582x; 1.4425x over previous
//
#include <hip/hip_runtime.h>

// GraphConv x2, CSR-pull, R6:
//   hist_rank: cnt[dst]++ AND rank[e] (atomic result kept, stored coalesced)
//   3-phase scan -> row_ptr
//   fill_csr2: srcs[row_ptr[dst]+rank] = src   (NO atomics)
//   xcast: x -> bf16 (25.6 MB, L2-friendlier gather target)
//   pull_f128(bf16): agg1[n] = sum x[srcs]     (f32 accum)
//   gemm_dual_relu: h = relu(agg1@Wr1^T + x@Wq1^T + b1)  in-place
//   gemm2_split: hr(bf16) = h@Wr2^T ; out = h@Wq2^T + b2
//   pull_add_f64(bf16): out += sum hr[srcs]
//
// R6 rationale: fill_csr was top (128 us) — latency chain dst-load ->
// atomic round-trip -> dependent scattered store (VALUBusy 0.3%). Rank
// trick removes the atomic from fill. Pulls gather 819/410 MB from f32
// arrays bigger than L2; bf16 staging halves gather bytes.

typedef float f4 __attribute__((ext_vector_type(4)));
typedef unsigned u4 __attribute__((ext_vector_type(4)));

#define KC 32
#define LDP 132   // 128 + 4 pad: keeps 16B alignment, breaks bank stride

__device__ __forceinline__ f4 relu4(f4 v) {
    f4 r;
    r[0] = fmaxf(v[0], 0.f); r[1] = fmaxf(v[1], 0.f);
    r[2] = fmaxf(v[2], 0.f); r[3] = fmaxf(v[3], 0.f);
    return r;
}

// pack two f32 -> bf16x2 (RNE); lo -> bits[15:0], hi -> bits[31:16]
__device__ __forceinline__ unsigned bfpair(float lo, float hi) {
    unsigned a = __float_as_uint(lo);
    unsigned b = __float_as_uint(hi);
    a = (a + 0x7FFFu + ((a >> 16) & 1u)) >> 16;
    b = (b + 0x7FFFu + ((b >> 16) & 1u)) & 0xFFFF0000u;
    return a | b;
}

// ---------------------------- CSR build ------------------------------------
// histogram + per-edge rank within its dst bucket (coalesced store)
__global__ void hist_rank(const int* __restrict__ dst, int* __restrict__ cnt,
                          int* __restrict__ rank, int E)
{
    int e = blockIdx.x * 256 + threadIdx.x;
    if (e < E) rank[e] = atomicAdd(&cnt[dst[e]], 1);
}

// phase 1: per-256-tile scan
__global__ __launch_bounds__(256) void scan_p1(const int* __restrict__ cnt,
                                               int* __restrict__ row_ptr,
                                               int* __restrict__ blk_sum, int N)
{
    __shared__ int ts[256];
    const int tid = threadIdx.x;
    const int i = blockIdx.x * 256 + tid;
    int v = (i < N) ? cnt[i] : 0;
    ts[tid] = v;
    __syncthreads();
#pragma unroll
    for (int off = 1; off < 256; off <<= 1) {
        int add = (tid >= off) ? ts[tid - off] : 0;
        __syncthreads();
        ts[tid] += add;
        __syncthreads();
    }
    if (i < N) row_ptr[i] = ts[tid] - v;          // exclusive within tile
    if (tid == 255) blk_sum[blockIdx.x] = ts[255];
}

// phase 2: single block, exclusive scan over nb block sums (nb <= 1024)
__global__ __launch_bounds__(1024) void scan_p2(int* __restrict__ blk_sum, int nb)
{
    __shared__ int ts[1024];
    const int tid = threadIdx.x;
    int v = (tid < nb) ? blk_sum[tid] : 0;
    ts[tid] = v;
    __syncthreads();
#pragma unroll
    for (int off = 1; off < 1024; off <<= 1) {
        int add = (tid >= off) ? ts[tid - off] : 0;
        __syncthreads();
        ts[tid] += add;
        __syncthreads();
    }
    if (tid < nb) blk_sum[tid] = ts[tid] - v;     // exclusive
}

// phase 3: add block offset -> final row_ptr
__global__ __launch_bounds__(256) void scan_p3(int* __restrict__ row_ptr,
                                               const int* __restrict__ blk_sum,
                                               int N, int E)
{
    const int i = blockIdx.x * 256 + threadIdx.x;
    if (i < N) row_ptr[i] += blk_sum[blockIdx.x];
    if (i == 0) row_ptr[N] = E;
}

// atomic-free bucket fill: 3 coalesced loads + L2 gather + scattered store
__global__ void fill_csr2(const int* __restrict__ src, const int* __restrict__ dst,
                          const int* __restrict__ rank,
                          const int* __restrict__ row_ptr,
                          int* __restrict__ srcs, int E)
{
    int e = blockIdx.x * 256 + threadIdx.x;
    if (e < E) srcs[row_ptr[dst[e]] + rank[e]] = src[e];
}

// ---------------------------- bf16 staging ---------------------------------
// x[N*128] f32 -> xb[N*64] bf16x2 ; thread handles 8 floats (4 uints)
__global__ void xcast(const float* __restrict__ x, unsigned* __restrict__ xb,
                      int n_u)   // n_u = N*64 uints
{
    int i = (blockIdx.x * 256 + threadIdx.x) * 4;
    if (i >= n_u) return;
    f4 a = *(const f4*)(x + (size_t)i * 2);
    f4 b = *(const f4*)(x + (size_t)i * 2 + 4);
    u4 o;
    o[0] = bfpair(a[0], a[1]); o[1] = bfpair(a[2], a[3]);
    o[2] = bfpair(b[0], b[1]); o[3] = bfpair(b[2], b[3]);
    *(u4*)(xb + i) = o;
}

// --------------------------- pull kernels ----------------------------------
// one wave per node; lane handles 2 feats (one bf16x2 uint), f32 accum
__global__ __launch_bounds__(256) void pull_f128(const unsigned* __restrict__ xb,
                                                 const int* __restrict__ row_ptr,
                                                 const int* __restrict__ srcs,
                                                 float* __restrict__ agg, int N)
{
    int w = (blockIdx.x * 256 + threadIdx.x) >> 6;
    int lane = threadIdx.x & 63;
    if (w >= N) return;
    const int beg = row_ptr[w], end = row_ptr[w + 1];
    float ax = 0.f, ay = 0.f;
    int j = beg;
    for (; j + 3 < end; j += 4) {
        int s0 = srcs[j], s1 = srcs[j + 1], s2 = srcs[j + 2], s3 = srcs[j + 3];
        unsigned u0 = xb[(size_t)s0 * 64 + lane];
        unsigned u1 = xb[(size_t)s1 * 64 + lane];
        unsigned u2 = xb[(size_t)s2 * 64 + lane];
        unsigned u3 = xb[(size_t)s3 * 64 + lane];
        ax += (__uint_as_float(u0 << 16) + __uint_as_float(u1 << 16))
            + (__uint_as_float(u2 << 16) + __uint_as_float(u3 << 16));
        ay += (__uint_as_float(u0 & 0xFFFF0000u) + __uint_as_float(u1 & 0xFFFF0000u))
            + (__uint_as_float(u2 & 0xFFFF0000u) + __uint_as_float(u3 & 0xFFFF0000u));
    }
    for (; j < end; ++j) {
        unsigned u0 = xb[(size_t)srcs[j] * 64 + lane];
        ax += __uint_as_float(u0 << 16);
        ay += __uint_as_float(u0 & 0xFFFF0000u);
    }
    float2 o; o.x = ax; o.y = ay;                 // feats 2*lane, 2*lane+1
    ((float2*)agg)[(size_t)w * 64 + lane] = o;
}

// two nodes per wave (32 lanes each); lane handles 2 feats; out += pulled sum
__global__ __launch_bounds__(256) void pull_add_f64(const unsigned* __restrict__ hrb,
                                                    const int* __restrict__ row_ptr,
                                                    const int* __restrict__ srcs,
                                                    float* __restrict__ out, int N)
{
    int t = blockIdx.x * 256 + threadIdx.x;
    int w = t >> 5;                // node
    int l = t & 31;                // uint col (feats 2l, 2l+1)
    if (w >= N) return;
    const int beg = row_ptr[w], end = row_ptr[w + 1];
    float ax = 0.f, ay = 0.f;
    int j = beg;
    for (; j + 3 < end; j += 4) {
        int s0 = srcs[j], s1 = srcs[j + 1], s2 = srcs[j + 2], s3 = srcs[j + 3];
        unsigned u0 = hrb[(size_t)s0 * 32 + l];
        unsigned u1 = hrb[(size_t)s1 * 32 + l];
        unsigned u2 = hrb[(size_t)s2 * 32 + l];
        unsigned u3 = hrb[(size_t)s3 * 32 + l];
        ax += (__uint_as_float(u0 << 16) + __uint_as_float(u1 << 16))
            + (__uint_as_float(u2 << 16) + __uint_as_float(u3 << 16));
        ay += (__uint_as_float(u0 & 0xFFFF0000u) + __uint_as_float(u1 & 0xFFFF0000u))
            + (__uint_as_float(u2 & 0xFFFF0000u) + __uint_as_float(u3 & 0xFFFF0000u));
    }
    for (; j < end; ++j) {
        unsigned u0 = hrb[(size_t)srcs[j] * 32 + l];
        ax += __uint_as_float(u0 << 16);
        ay += __uint_as_float(u0 & 0xFFFF0000u);
    }
    float2* po = (float2*)out + (size_t)w * 32 + l;
    float2 cur = *po;
    cur.x += ax; cur.y += ay;
    *po = cur;
}

// ------------- layer 1: h = relu(A1@W1^T + A2@W2^T + bias), 128 out ----------
// block: 256 threads, tile 128 nodes x 128 outs, thread = 8 nodes x 8 outs.
// Safe with out == A1 (each block writes only rows it alone reads).
__global__ __launch_bounds__(256) void gemm_dual_relu(
    const float* __restrict__ A1, const float* __restrict__ A2,
    const float* __restrict__ W1, const float* __restrict__ W2,
    const float* __restrict__ bias, float* __restrict__ out, int N)
{
    __shared__ float sA[KC][LDP];
    __shared__ float sW[KC][LDP];
    const int tid = threadIdx.x;
    const int ng = tid >> 4;
    const int og = tid & 15;
    const int n0 = blockIdx.x * 128;

    f4 acc[8][2];
#pragma unroll
    for (int i = 0; i < 8; ++i) { acc[i][0] = 0.f; acc[i][1] = 0.f; }

#pragma unroll 1
    for (int chunk = 0; chunk < 8; ++chunk) {
        const float* A = (chunk < 4) ? A1 : A2;
        const float* W = (chunk < 4) ? W1 : W2;
        const int kc = (chunk & 3) * KC;
#pragma unroll
        for (int i = 0; i < 4; ++i) {
            int fidx = tid + i * 256;
            int r = fidx >> 3;
            int k4 = fidx & 7;
            int n = n0 + r; if (n >= N) n = N - 1;
            f4 va = *(const f4*)(A + (size_t)n * 128 + kc + k4 * 4);
            sA[k4*4+0][r] = va[0]; sA[k4*4+1][r] = va[1];
            sA[k4*4+2][r] = va[2]; sA[k4*4+3][r] = va[3];
            f4 vw = *(const f4*)(W + (size_t)r * 128 + kc + k4 * 4);
            sW[k4*4+0][r] = vw[0]; sW[k4*4+1][r] = vw[1];
            sW[k4*4+2][r] = vw[2]; sW[k4*4+3][r] = vw[3];
        }
        __syncthreads();
#pragma unroll
        for (int k = 0; k < KC; ++k) {
            f4 a0 = *(const f4*)&sA[k][ng*8];
            f4 a1 = *(const f4*)&sA[k][ng*8 + 4];
            f4 w0 = *(const f4*)&sW[k][og*8];
            f4 w1 = *(const f4*)&sW[k][og*8 + 4];
#pragma unroll
            for (int i = 0; i < 4; ++i) {
                acc[i][0]   += a0[i] * w0;
                acc[i][1]   += a0[i] * w1;
                acc[i+4][0] += a1[i] * w0;
                acc[i+4][1] += a1[i] * w1;
            }
        }
        __syncthreads();
    }

    f4 b0 = *(const f4*)(bias + og*8);
    f4 b1 = *(const f4*)(bias + og*8 + 4);
#pragma unroll
    for (int i = 0; i < 8; ++i) {
        int n = n0 + ng * 8 + i;
        if (n < N) {
            *(f4*)(out + (size_t)n * 128 + og*8)     = relu4(acc[i][0] + b0);
            *(f4*)(out + (size_t)n * 128 + og*8 + 4) = relu4(acc[i][1] + b1);
        }
    }
}

// ------- layer 2: cols 0..63 -> hr(bf16) = H@Wr^T ; cols 64..127 -> out = H@Wq^T + b2
__global__ __launch_bounds__(256) void gemm2_split(
    const float* __restrict__ H,
    const float* __restrict__ Wr, const float* __restrict__ Wq,
    const float* __restrict__ b2,
    unsigned* __restrict__ hrb, float* __restrict__ outp, int N)
{
    __shared__ float sA[KC][LDP];
    __shared__ float sW[KC][LDP];
    const int tid = threadIdx.x;
    const int ng = tid >> 4;
    const int og = tid & 15;
    const int n0 = blockIdx.x * 128;

    f4 acc[8][2];
#pragma unroll
    for (int i = 0; i < 8; ++i) { acc[i][0] = 0.f; acc[i][1] = 0.f; }

#pragma unroll 1
    for (int chunk = 0; chunk < 4; ++chunk) {
        const int kc = chunk * KC;
#pragma unroll
        for (int i = 0; i < 4; ++i) {
            int fidx = tid + i * 256;
            int r = fidx >> 3;
            int k4 = fidx & 7;
            int n = n0 + r; if (n >= N) n = N - 1;
            f4 va = *(const f4*)(H + (size_t)n * 128 + kc + k4 * 4);
            sA[k4*4+0][r] = va[0]; sA[k4*4+1][r] = va[1];
            sA[k4*4+2][r] = va[2]; sA[k4*4+3][r] = va[3];
            const float* wrow = (r < 64) ? (Wr + (size_t)r * 128)
                                         : (Wq + (size_t)(r - 64) * 128);
            f4 vw = *(const f4*)(wrow + kc + k4 * 4);
            sW[k4*4+0][r] = vw[0]; sW[k4*4+1][r] = vw[1];
            sW[k4*4+2][r] = vw[2]; sW[k4*4+3][r] = vw[3];
        }
        __syncthreads();
#pragma unroll
        for (int k = 0; k < KC; ++k) {
            f4 a0 = *(const f4*)&sA[k][ng*8];
            f4 a1 = *(const f4*)&sA[k][ng*8 + 4];
            f4 w0 = *(const f4*)&sW[k][og*8];
            f4 w1 = *(const f4*)&sW[k][og*8 + 4];
#pragma unroll
            for (int i = 0; i < 4; ++i) {
                acc[i][0]   += a0[i] * w0;
                acc[i][1]   += a0[i] * w1;
                acc[i+4][0] += a1[i] * w0;
                acc[i+4][1] += a1[i] * w1;
            }
        }
        __syncthreads();
    }

    if (og < 8) {
        // rel half -> hr as bf16x2 (pull_add gathers it)
#pragma unroll
        for (int i = 0; i < 8; ++i) {
            int n = n0 + ng * 8 + i;
            if (n < N) {
                u4 o;
                o[0] = bfpair(acc[i][0][0], acc[i][0][1]);
                o[1] = bfpair(acc[i][0][2], acc[i][0][3]);
                o[2] = bfpair(acc[i][1][0], acc[i][1][1]);
                o[3] = bfpair(acc[i][1][2], acc[i][1][3]);
                *(u4*)(hrb + (size_t)n * 32 + og * 4) = o;
            }
        }
    } else {
        const int oq = (og - 8) * 8;
        f4 b0 = *(const f4*)(b2 + oq);
        f4 b1 = *(const f4*)(b2 + oq + 4);
#pragma unroll
        for (int i = 0; i < 8; ++i) {
            int n = n0 + ng * 8 + i;
            if (n < N) {
                *(f4*)(outp + (size_t)n * 64 + oq)     = acc[i][0] + b0;
                *(f4*)(outp + (size_t)n * 64 + oq + 4) = acc[i][1] + b1;
            }
        }
    }
}

extern "C" void kernel_launch(void* const* d_in, const int* in_sizes, int n_in,
                              void* d_out, int out_size, void* d_ws, size_t ws_size,
                              hipStream_t stream)
{
    const float* x       = (const float*)d_in[0];
    const int*   ei      = (const int*)d_in[1];
    const float* w_rel1  = (const float*)d_in[2];
    const float* b_rel1  = (const float*)d_in[3];
    const float* w_root1 = (const float*)d_in[4];
    const float* w_rel2  = (const float*)d_in[5];
    const float* b_rel2  = (const float*)d_in[6];
    const float* w_root2 = (const float*)d_in[7];
    float* out = (float*)d_out;

    const int N = in_sizes[0] / 128;
    const int E = in_sizes[1] / 2;
    const int* src = ei;        // edge_index[0]
    const int* dst = ei + E;    // edge_index[1]

    // workspace (~90 MB):
    //   agg1/h [N*128 f32] | xb [N*64 u32] (bf16 x; reused as hrb [N*32 u32])
    //   | srcs [E] | rank [E] | row_ptr [N+1] | cnt [N] | blk_sum [1024]
    float*    agg1    = (float*)d_ws;
    unsigned* xb      = (unsigned*)(agg1 + (size_t)N * 128);
    unsigned* hrb     = xb;                           // alias: xb dead after pull_f128
    int*      srcs    = (int*)(xb + (size_t)N * 64);
    int*      rank    = srcs + E;
    int*      row_ptr = rank + E;
    int*      cnt     = row_ptr + (N + 1);
    int*      blk_sum = cnt + N;

    const int nb = (N + 255) / 256;                   // scan tiles (N<=262144)
    const int egrid = (E + 255) / 256;

    // ---- bf16 staging of x (independent of CSR build) ----
    xcast<<<(N * 64 / 4 + 255) / 256, 256, 0, stream>>>(x, xb, N * 64);

    // ---- CSR build (shared by both layers) ----
    hipMemsetAsync(cnt, 0, (size_t)N * sizeof(int), stream);
    hist_rank<<<egrid, 256, 0, stream>>>(dst, cnt, rank, E);
    scan_p1<<<nb, 256, 0, stream>>>(cnt, row_ptr, blk_sum, N);
    scan_p2<<<1, 1024, 0, stream>>>(blk_sum, nb);
    scan_p3<<<nb, 256, 0, stream>>>(row_ptr, blk_sum, N, E);
    fill_csr2<<<egrid, 256, 0, stream>>>(src, dst, rank, row_ptr, srcs, E);

    // 1. agg1 = pull-sum xb
    pull_f128<<<(N * 64 + 255) / 256, 256, 0, stream>>>(xb, row_ptr, srcs, agg1, N);
    // 2. h = relu(agg1@Wr1^T + x@Wq1^T + b1)   (in-place: h == agg1)
    {
        int grid = (N + 127) / 128;
        gemm_dual_relu<<<grid, 256, 0, stream>>>(agg1, x, w_rel1, w_root1, b_rel1, agg1, N);
        // 3. hr(bf16) = h@Wr2^T ; out = h@Wq2^T + b2
        gemm2_split<<<grid, 256, 0, stream>>>(agg1, w_rel2, w_root2, b_rel2, hrb, out, N);
    }
    // 4. out += pull-sum hrb
    pull_add_f64<<<(N * 32 + 255) / 256, 256, 0, stream>>>(hrb, row_ptr, srcs, out, N);
}

// Round 7
// 320.551 us; speedup vs baseline: 60.2098x; 1.1792x over previous
//
#include <hip/hip_runtime.h>

// GraphConv x2, CSR-pull + f16 MFMA GEMMs (R7):
//   wcast: weights -> f16 ; xcast: x -> f16
//   CSR build: hist_rank -> 3-phase scan -> atomic-free fill
//   pull_h128: aggh(f16) = sum xh[srcs]            (f32 accum)
//   mfma_gemm1: h(f16) = relu(aggh@Wr1^T + xh@Wq1^T + b1)   [K=256 dual, MFMA]
//   mfma_gemm2: hr(f16) = h@Wr2^T ; out(f32) = h@Wq2^T + b2 [K=128, MFMA]
//   pull_add_h64: out += sum hr[srcs]
//
// R7 rationale: gemm_dual_relu was top (106 us, VALUBusy 47%, 1.1e7 LDS bank
// conflicts) — f32 vector GEMM capped by VALU + 4-way sW conflicts. CDNA4 has
// no f32 MFMA, so the staged path moves to f16 (4x better mantissa than the
// bf16 it replaces; all values << f16 range) and both GEMMs use
// mfma_f32_16x16x32_f16 with f32 accumulation. No LDS: B-frags broadcast from
// L2 (weights are 64 KB), A-frags are per-row 16B loads reused across the
// k-loop via L1/L2. K-permutation invariance makes contiguous-8k frag loads
// correct for both operands regardless of the hw k interleave.

typedef float f4 __attribute__((ext_vector_type(4)));
typedef _Float16 h8 __attribute__((ext_vector_type(8)));
typedef _Float16 h2 __attribute__((ext_vector_type(2)));

__device__ __forceinline__ float2 h2f(unsigned u) {
    h2 p = __builtin_bit_cast(h2, u);
    float2 r; r.x = (float)p[0]; r.y = (float)p[1];
    return r;
}
__device__ __forceinline__ unsigned f2h(float a, float b) {
    h2 p; p[0] = (_Float16)a; p[1] = (_Float16)b;
    return __builtin_bit_cast(unsigned, p);
}

// ---------------------------- casts ----------------------------------------
// wbuf layout (halves): wr1h @0 [128x128] | wq1h @16384 | wr2h @32768 [64x128]
// | wq2h @40960  (total 49152)
__global__ void wcast(const float* __restrict__ wr1, const float* __restrict__ wq1,
                      const float* __restrict__ wr2, const float* __restrict__ wq2,
                      _Float16* __restrict__ wb)
{
    int i = blockIdx.x * 256 + threadIdx.x;
    if (i < 16384)      wb[i] = (_Float16)wr1[i];
    else if (i < 32768) wb[i] = (_Float16)wq1[i - 16384];
    else if (i < 40960) wb[i] = (_Float16)wr2[i - 32768];
    else if (i < 49152) wb[i] = (_Float16)wq2[i - 40960];
}

__global__ void xcast(const float* __restrict__ x, _Float16* __restrict__ xh,
                      long n)   // n = N*128, multiple of 8
{
    long i = (long)(blockIdx.x * 256 + threadIdx.x) * 8;
    if (i >= n) return;
    f4 a = *(const f4*)(x + i);
    f4 b = *(const f4*)(x + i + 4);
    h8 o;
    o[0] = (_Float16)a[0]; o[1] = (_Float16)a[1];
    o[2] = (_Float16)a[2]; o[3] = (_Float16)a[3];
    o[4] = (_Float16)b[0]; o[5] = (_Float16)b[1];
    o[6] = (_Float16)b[2]; o[7] = (_Float16)b[3];
    *(h8*)(xh + i) = o;
}

// ---------------------------- CSR build ------------------------------------
__global__ void hist_rank(const int* __restrict__ dst, int* __restrict__ cnt,
                          int* __restrict__ rank, int E)
{
    int e = blockIdx.x * 256 + threadIdx.x;
    if (e < E) rank[e] = atomicAdd(&cnt[dst[e]], 1);
}

__global__ __launch_bounds__(256) void scan_p1(const int* __restrict__ cnt,
                                               int* __restrict__ row_ptr,
                                               int* __restrict__ blk_sum, int N)
{
    __shared__ int ts[256];
    const int tid = threadIdx.x;
    const int i = blockIdx.x * 256 + tid;
    int v = (i < N) ? cnt[i] : 0;
    ts[tid] = v;
    __syncthreads();
#pragma unroll
    for (int off = 1; off < 256; off <<= 1) {
        int add = (tid >= off) ? ts[tid - off] : 0;
        __syncthreads();
        ts[tid] += add;
        __syncthreads();
    }
    if (i < N) row_ptr[i] = ts[tid] - v;
    if (tid == 255) blk_sum[blockIdx.x] = ts[255];
}

__global__ __launch_bounds__(1024) void scan_p2(int* __restrict__ blk_sum, int nb)
{
    __shared__ int ts[1024];
    const int tid = threadIdx.x;
    int v = (tid < nb) ? blk_sum[tid] : 0;
    ts[tid] = v;
    __syncthreads();
#pragma unroll
    for (int off = 1; off < 1024; off <<= 1) {
        int add = (tid >= off) ? ts[tid - off] : 0;
        __syncthreads();
        ts[tid] += add;
        __syncthreads();
    }
    if (tid < nb) blk_sum[tid] = ts[tid] - v;
}

__global__ __launch_bounds__(256) void scan_p3(int* __restrict__ row_ptr,
                                               const int* __restrict__ blk_sum,
                                               int N, int E)
{
    const int i = blockIdx.x * 256 + threadIdx.x;
    if (i < N) row_ptr[i] += blk_sum[blockIdx.x];
    if (i == 0) row_ptr[N] = E;
}

__global__ void fill_csr2(const int* __restrict__ src, const int* __restrict__ dst,
                          const int* __restrict__ rank,
                          const int* __restrict__ row_ptr,
                          int* __restrict__ srcs, int E)
{
    int e = blockIdx.x * 256 + threadIdx.x;
    if (e < E) srcs[row_ptr[dst[e]] + rank[e]] = src[e];
}

// --------------------------- pull kernels ----------------------------------
// one wave per node; lane handles 2 feats (one f16x2 uint); f16 out
__global__ __launch_bounds__(256) void pull_h128(const unsigned* __restrict__ xh2,
                                                 const int* __restrict__ row_ptr,
                                                 const int* __restrict__ srcs,
                                                 unsigned* __restrict__ aggh2, int N)
{
    int w = (blockIdx.x * 256 + threadIdx.x) >> 6;
    int lane = threadIdx.x & 63;
    if (w >= N) return;
    const int beg = row_ptr[w], end = row_ptr[w + 1];
    float ax = 0.f, ay = 0.f;
    int j = beg;
    for (; j + 3 < end; j += 4) {
        int s0 = srcs[j], s1 = srcs[j + 1], s2 = srcs[j + 2], s3 = srcs[j + 3];
        float2 v0 = h2f(xh2[(size_t)s0 * 64 + lane]);
        float2 v1 = h2f(xh2[(size_t)s1 * 64 + lane]);
        float2 v2 = h2f(xh2[(size_t)s2 * 64 + lane]);
        float2 v3 = h2f(xh2[(size_t)s3 * 64 + lane]);
        ax += (v0.x + v1.x) + (v2.x + v3.x);
        ay += (v0.y + v1.y) + (v2.y + v3.y);
    }
    for (; j < end; ++j) {
        float2 v0 = h2f(xh2[(size_t)srcs[j] * 64 + lane]);
        ax += v0.x; ay += v0.y;
    }
    aggh2[(size_t)w * 64 + lane] = f2h(ax, ay);
}

// two nodes per wave (32 lanes each); lane handles 2 feats; out(f32) += sum
__global__ __launch_bounds__(256) void pull_add_h64(const unsigned* __restrict__ hrb,
                                                    const int* __restrict__ row_ptr,
                                                    const int* __restrict__ srcs,
                                                    float* __restrict__ out, int N)
{
    int t = blockIdx.x * 256 + threadIdx.x;
    int w = t >> 5;
    int l = t & 31;
    if (w >= N) return;
    const int beg = row_ptr[w], end = row_ptr[w + 1];
    float ax = 0.f, ay = 0.f;
    int j = beg;
    for (; j + 3 < end; j += 4) {
        int s0 = srcs[j], s1 = srcs[j + 1], s2 = srcs[j + 2], s3 = srcs[j + 3];
        float2 v0 = h2f(hrb[(size_t)s0 * 32 + l]);
        float2 v1 = h2f(hrb[(size_t)s1 * 32 + l]);
        float2 v2 = h2f(hrb[(size_t)s2 * 32 + l]);
        float2 v3 = h2f(hrb[(size_t)s3 * 32 + l]);
        ax += (v0.x + v1.x) + (v2.x + v3.x);
        ay += (v0.y + v1.y) + (v2.y + v3.y);
    }
    for (; j < end; ++j) {
        float2 v0 = h2f(hrb[(size_t)srcs[j] * 32 + l]);
        ax += v0.x; ay += v0.y;
    }
    float2* po = (float2*)out + (size_t)w * 32 + l;
    float2 cur = *po;
    cur.x += ax; cur.y += ay;
    *po = cur;
}

// ----------------------- MFMA GEMM 1 (K=256 dual) --------------------------
// h = relu([aggh|xh] @ [Wr1|Wq1]^T + b1). 4 waves/block, 32 rows/wave,
// full 128 output cols per wave. acc f4[2][8]; frags direct from global.
__global__ __launch_bounds__(256) void mfma_gemm1(
    const _Float16* __restrict__ aggh, const _Float16* __restrict__ xh,
    const _Float16* __restrict__ wb,   // wr1h @0, wq1h @16384
    const float* __restrict__ b1,
    _Float16* __restrict__ h, int N)
{
    const int w  = threadIdx.x >> 6;
    const int l  = threadIdx.x & 63;
    const int lr = l & 15;
    const int kg = l >> 4;
    const int base = blockIdx.x * 128 + w * 32;
    const int r0 = min(base + lr,      N - 1);
    const int r1 = min(base + 16 + lr, N - 1);

    f4 acc[2][8];
#pragma unroll
    for (int s = 0; s < 2; ++s)
#pragma unroll
        for (int n = 0; n < 8; ++n) acc[s][n] = 0.f;

#pragma unroll 1
    for (int kk = 0; kk < 8; ++kk) {
        const _Float16* A = (kk < 4) ? aggh : xh;
        const _Float16* B = (kk < 4) ? wb : (wb + 16384);
        const int k0 = (kk & 3) * 32 + kg * 8;
        h8 a0 = *(const h8*)(A + (size_t)r0 * 128 + k0);
        h8 a1 = *(const h8*)(A + (size_t)r1 * 128 + k0);
#pragma unroll
        for (int n = 0; n < 8; ++n) {
            h8 bf = *(const h8*)(B + (size_t)(n * 16 + lr) * 128 + k0);
            acc[0][n] = __builtin_amdgcn_mfma_f32_16x16x32_f16(a0, bf, acc[0][n], 0, 0, 0);
            acc[1][n] = __builtin_amdgcn_mfma_f32_16x16x32_f16(a1, bf, acc[1][n], 0, 0, 0);
        }
    }

    const int ro = kg * 4;   // D: row = (l>>4)*4 + j, col = l&15
#pragma unroll
    for (int s = 0; s < 2; ++s)
#pragma unroll
        for (int n = 0; n < 8; ++n) {
            const int col = n * 16 + lr;
            const float bias = b1[col];
#pragma unroll
            for (int j = 0; j < 4; ++j) {
                int r = base + s * 16 + ro + j;
                if (r < N)
                    h[(size_t)r * 128 + col] = (_Float16)fmaxf(acc[s][n][j] + bias, 0.f);
            }
        }
}

// ----------------------- MFMA GEMM 2 (K=128 split) -------------------------
// cols 0..63 -> hr(f16) = h@Wr2^T ; cols 64..127 -> out(f32) = h@Wq2^T + b2
__global__ __launch_bounds__(256) void mfma_gemm2(
    const _Float16* __restrict__ h,
    const _Float16* __restrict__ wb2,  // wr2h @0, wq2h @8192 (contiguous 128x128)
    const float* __restrict__ b2,
    _Float16* __restrict__ hrh, float* __restrict__ outp, int N)
{
    const int w  = threadIdx.x >> 6;
    const int l  = threadIdx.x & 63;
    const int lr = l & 15;
    const int kg = l >> 4;
    const int base = blockIdx.x * 128 + w * 32;
    const int r0 = min(base + lr,      N - 1);
    const int r1 = min(base + 16 + lr, N - 1);

    f4 acc[2][8];
#pragma unroll
    for (int s = 0; s < 2; ++s)
#pragma unroll
        for (int n = 0; n < 8; ++n) acc[s][n] = 0.f;

#pragma unroll 1
    for (int kk = 0; kk < 4; ++kk) {
        const int k0 = kk * 32 + kg * 8;
        h8 a0 = *(const h8*)(h + (size_t)r0 * 128 + k0);
        h8 a1 = *(const h8*)(h + (size_t)r1 * 128 + k0);
#pragma unroll
        for (int n = 0; n < 8; ++n) {
            h8 bf = *(const h8*)(wb2 + (size_t)(n * 16 + lr) * 128 + k0);
            acc[0][n] = __builtin_amdgcn_mfma_f32_16x16x32_f16(a0, bf, acc[0][n], 0, 0, 0);
            acc[1][n] = __builtin_amdgcn_mfma_f32_16x16x32_f16(a1, bf, acc[1][n], 0, 0, 0);
        }
    }

    const int ro = kg * 4;
#pragma unroll
    for (int s = 0; s < 2; ++s)
#pragma unroll
        for (int n = 0; n < 8; ++n) {
            const int col = n * 16 + lr;
#pragma unroll
            for (int j = 0; j < 4; ++j) {
                int r = base + s * 16 + ro + j;
                if (r < N) {
                    if (n < 4) {
                        hrh[(size_t)r * 64 + col] = (_Float16)acc[s][n][j];
                    } else {
                        outp[(size_t)r * 64 + (col - 64)] = acc[s][n][j] + b2[col - 64];
                    }
                }
            }
        }
}

extern "C" void kernel_launch(void* const* d_in, const int* in_sizes, int n_in,
                              void* d_out, int out_size, void* d_ws, size_t ws_size,
                              hipStream_t stream)
{
    const float* x       = (const float*)d_in[0];
    const int*   ei      = (const int*)d_in[1];
    const float* w_rel1  = (const float*)d_in[2];
    const float* b_rel1  = (const float*)d_in[3];
    const float* w_root1 = (const float*)d_in[4];
    const float* w_rel2  = (const float*)d_in[5];
    const float* b_rel2  = (const float*)d_in[6];
    const float* w_root2 = (const float*)d_in[7];
    float* out = (float*)d_out;

    const int N = in_sizes[0] / 128;
    const int E = in_sizes[1] / 2;
    const int* src = ei;        // edge_index[0]
    const int* dst = ei + E;    // edge_index[1]

    // workspace (~91 MB), all f16 tensors [row][feat]:
    //   xh [N*128] | aggh [N*128] (hr aliases it) | h [N*128] | wbuf [49152]
    //   | srcs [E] | rank [E] | row_ptr [N+1] | cnt [N] | blk_sum [1024]
    _Float16* xh    = (_Float16*)d_ws;
    _Float16* aggh  = xh + (size_t)N * 128;
    _Float16* hbuf  = aggh + (size_t)N * 128;
    _Float16* hrh   = aggh;                         // alias: aggh dead after gemm1
    _Float16* wbuf  = hbuf + (size_t)N * 128;
    int*      srcs    = (int*)(wbuf + 49152);
    int*      rank    = srcs + E;
    int*      row_ptr = rank + E;
    int*      cnt     = row_ptr + (N + 1);
    int*      blk_sum = cnt + N;

    const int nb = (N + 255) / 256;
    const int egrid = (E + 255) / 256;

    // ---- f16 staging ----
    wcast<<<(49152 + 255) / 256, 256, 0, stream>>>(w_rel1, w_root1, w_rel2, w_root2, wbuf);
    xcast<<<(N * 128 / 8 + 255) / 256, 256, 0, stream>>>(x, xh, (long)N * 128);

    // ---- CSR build (shared by both layers) ----
    hipMemsetAsync(cnt, 0, (size_t)N * sizeof(int), stream);
    hist_rank<<<egrid, 256, 0, stream>>>(dst, cnt, rank, E);
    scan_p1<<<nb, 256, 0, stream>>>(cnt, row_ptr, blk_sum, N);
    scan_p2<<<1, 1024, 0, stream>>>(blk_sum, nb);
    scan_p3<<<nb, 256, 0, stream>>>(row_ptr, blk_sum, N, E);
    fill_csr2<<<egrid, 256, 0, stream>>>(src, dst, rank, row_ptr, srcs, E);

    // 1. aggh = pull-sum xh
    pull_h128<<<(N * 64 + 255) / 256, 256, 0, stream>>>(
        (const unsigned*)xh, row_ptr, srcs, (unsigned*)aggh, N);

    // 2/3. MFMA GEMMs
    {
        int grid = (N + 127) / 128;
        mfma_gemm1<<<grid, 256, 0, stream>>>(aggh, xh, wbuf, b_rel1, hbuf, N);
        mfma_gemm2<<<grid, 256, 0, stream>>>(hbuf, wbuf + 32768, b_rel2, hrh, out, N);
    }

    // 4. out += pull-sum hr
    pull_add_h64<<<(N * 32 + 255) / 256, 256, 0, stream>>>(
        (const unsigned*)hrh, row_ptr, srcs, out, N);
}

// Round 8
// 316.983 us; speedup vs baseline: 60.8876x; 1.0113x over previous
//
#include <hip/hip_runtime.h>

// GraphConv x2, CSR-pull + f16 MFMA GEMMs (R8):
//   wcast/xcast -> f16 staging
//   CSR build: hist_rank (LINE-PADDED counters) -> 3-phase scan -> atomic-free fill
//   pull_h128: aggh(f16) = sum xh[srcs]            (f32 accum)
//   mfma_gemm1: h(f16) = relu(aggh@Wr1^T + xh@Wq1^T + b1)   [K=256 dual, MFMA]
//   mfma_gemm2: hr(f16) = h@Wr2^T ; out(f32) = h@Wq2^T + b2 [K=128, MFMA]
//   pull_add_h64: out += sum hr[srcs]
//
// R8 rationale: hist_rank was top (75 us, VALUBusy 0.4%, HBM 10%) — 1.6M
// device-scope atomics over a 400 KB cnt array = 256 RMWs per 64B line,
// serialized at the coherence point (~6250 lines x 256 x ~15cy / ~128 banks
// ≈ 75 us, matching). Padding counters to one per 64B line (cnt[i*16],
// 6.4 MB) cuts per-line contention 16x. Scan reads stride-16; memset grows
// to 6.4 MB — both ~1-2 us.

typedef float f4 __attribute__((ext_vector_type(4)));
typedef _Float16 h8 __attribute__((ext_vector_type(8)));
typedef _Float16 h2 __attribute__((ext_vector_type(2)));

#define CPAD 16   // counters padded to one per 64B cache line

__device__ __forceinline__ float2 h2f(unsigned u) {
    h2 p = __builtin_bit_cast(h2, u);
    float2 r; r.x = (float)p[0]; r.y = (float)p[1];
    return r;
}
__device__ __forceinline__ unsigned f2h(float a, float b) {
    h2 p; p[0] = (_Float16)a; p[1] = (_Float16)b;
    return __builtin_bit_cast(unsigned, p);
}

// ---------------------------- casts ----------------------------------------
// wbuf layout (halves): wr1h @0 [128x128] | wq1h @16384 | wr2h @32768 [64x128]
// | wq2h @40960  (total 49152)
__global__ void wcast(const float* __restrict__ wr1, const float* __restrict__ wq1,
                      const float* __restrict__ wr2, const float* __restrict__ wq2,
                      _Float16* __restrict__ wb)
{
    int i = blockIdx.x * 256 + threadIdx.x;
    if (i < 16384)      wb[i] = (_Float16)wr1[i];
    else if (i < 32768) wb[i] = (_Float16)wq1[i - 16384];
    else if (i < 40960) wb[i] = (_Float16)wr2[i - 32768];
    else if (i < 49152) wb[i] = (_Float16)wq2[i - 40960];
}

__global__ void xcast(const float* __restrict__ x, _Float16* __restrict__ xh,
                      long n)   // n = N*128, multiple of 8
{
    long i = (long)(blockIdx.x * 256 + threadIdx.x) * 8;
    if (i >= n) return;
    f4 a = *(const f4*)(x + i);
    f4 b = *(const f4*)(x + i + 4);
    h8 o;
    o[0] = (_Float16)a[0]; o[1] = (_Float16)a[1];
    o[2] = (_Float16)a[2]; o[3] = (_Float16)a[3];
    o[4] = (_Float16)b[0]; o[5] = (_Float16)b[1];
    o[6] = (_Float16)b[2]; o[7] = (_Float16)b[3];
    *(h8*)(xh + i) = o;
}

// ---------------------------- CSR build ------------------------------------
// histogram (line-padded counters) + per-edge rank within its dst bucket
__global__ void hist_rank(const int* __restrict__ dst, int* __restrict__ cnt,
                          int* __restrict__ rank, int E)
{
    int e = blockIdx.x * 256 + threadIdx.x;
    if (e < E) rank[e] = atomicAdd(&cnt[(size_t)dst[e] * CPAD], 1);
}

__global__ __launch_bounds__(256) void scan_p1(const int* __restrict__ cnt,
                                               int* __restrict__ row_ptr,
                                               int* __restrict__ blk_sum, int N)
{
    __shared__ int ts[256];
    const int tid = threadIdx.x;
    const int i = blockIdx.x * 256 + tid;
    int v = (i < N) ? cnt[(size_t)i * CPAD] : 0;
    ts[tid] = v;
    __syncthreads();
#pragma unroll
    for (int off = 1; off < 256; off <<= 1) {
        int add = (tid >= off) ? ts[tid - off] : 0;
        __syncthreads();
        ts[tid] += add;
        __syncthreads();
    }
    if (i < N) row_ptr[i] = ts[tid] - v;
    if (tid == 255) blk_sum[blockIdx.x] = ts[255];
}

__global__ __launch_bounds__(1024) void scan_p2(int* __restrict__ blk_sum, int nb)
{
    __shared__ int ts[1024];
    const int tid = threadIdx.x;
    int v = (tid < nb) ? blk_sum[tid] : 0;
    ts[tid] = v;
    __syncthreads();
#pragma unroll
    for (int off = 1; off < 1024; off <<= 1) {
        int add = (tid >= off) ? ts[tid - off] : 0;
        __syncthreads();
        ts[tid] += add;
        __syncthreads();
    }
    if (tid < nb) blk_sum[tid] = ts[tid] - v;
}

__global__ __launch_bounds__(256) void scan_p3(int* __restrict__ row_ptr,
                                               const int* __restrict__ blk_sum,
                                               int N, int E)
{
    const int i = blockIdx.x * 256 + threadIdx.x;
    if (i < N) row_ptr[i] += blk_sum[blockIdx.x];
    if (i == 0) row_ptr[N] = E;
}

__global__ void fill_csr2(const int* __restrict__ src, const int* __restrict__ dst,
                          const int* __restrict__ rank,
                          const int* __restrict__ row_ptr,
                          int* __restrict__ srcs, int E)
{
    int e = blockIdx.x * 256 + threadIdx.x;
    if (e < E) srcs[row_ptr[dst[e]] + rank[e]] = src[e];
}

// --------------------------- pull kernels ----------------------------------
// one wave per node; lane handles 2 feats (one f16x2 uint); f16 out
__global__ __launch_bounds__(256) void pull_h128(const unsigned* __restrict__ xh2,
                                                 const int* __restrict__ row_ptr,
                                                 const int* __restrict__ srcs,
                                                 unsigned* __restrict__ aggh2, int N)
{
    int w = (blockIdx.x * 256 + threadIdx.x) >> 6;
    int lane = threadIdx.x & 63;
    if (w >= N) return;
    const int beg = row_ptr[w], end = row_ptr[w + 1];
    float ax = 0.f, ay = 0.f;
    int j = beg;
    for (; j + 3 < end; j += 4) {
        int s0 = srcs[j], s1 = srcs[j + 1], s2 = srcs[j + 2], s3 = srcs[j + 3];
        float2 v0 = h2f(xh2[(size_t)s0 * 64 + lane]);
        float2 v1 = h2f(xh2[(size_t)s1 * 64 + lane]);
        float2 v2 = h2f(xh2[(size_t)s2 * 64 + lane]);
        float2 v3 = h2f(xh2[(size_t)s3 * 64 + lane]);
        ax += (v0.x + v1.x) + (v2.x + v3.x);
        ay += (v0.y + v1.y) + (v2.y + v3.y);
    }
    for (; j < end; ++j) {
        float2 v0 = h2f(xh2[(size_t)srcs[j] * 64 + lane]);
        ax += v0.x; ay += v0.y;
    }
    aggh2[(size_t)w * 64 + lane] = f2h(ax, ay);
}

// two nodes per wave (32 lanes each); lane handles 2 feats; out(f32) += sum
__global__ __launch_bounds__(256) void pull_add_h64(const unsigned* __restrict__ hrb,
                                                    const int* __restrict__ row_ptr,
                                                    const int* __restrict__ srcs,
                                                    float* __restrict__ out, int N)
{
    int t = blockIdx.x * 256 + threadIdx.x;
    int w = t >> 5;
    int l = t & 31;
    if (w >= N) return;
    const int beg = row_ptr[w], end = row_ptr[w + 1];
    float ax = 0.f, ay = 0.f;
    int j = beg;
    for (; j + 3 < end; j += 4) {
        int s0 = srcs[j], s1 = srcs[j + 1], s2 = srcs[j + 2], s3 = srcs[j + 3];
        float2 v0 = h2f(hrb[(size_t)s0 * 32 + l]);
        float2 v1 = h2f(hrb[(size_t)s1 * 32 + l]);
        float2 v2 = h2f(hrb[(size_t)s2 * 32 + l]);
        float2 v3 = h2f(hrb[(size_t)s3 * 32 + l]);
        ax += (v0.x + v1.x) + (v2.x + v3.x);
        ay += (v0.y + v1.y) + (v2.y + v3.y);
    }
    for (; j < end; ++j) {
        float2 v0 = h2f(hrb[(size_t)srcs[j] * 32 + l]);
        ax += v0.x; ay += v0.y;
    }
    float2* po = (float2*)out + (size_t)w * 32 + l;
    float2 cur = *po;
    cur.x += ax; cur.y += ay;
    *po = cur;
}

// ----------------------- MFMA GEMM 1 (K=256 dual) --------------------------
// h = relu([aggh|xh] @ [Wr1|Wq1]^T + b1). 4 waves/block, 32 rows/wave,
// full 128 output cols per wave. acc f4[2][8]; frags direct from global.
__global__ __launch_bounds__(256) void mfma_gemm1(
    const _Float16* __restrict__ aggh, const _Float16* __restrict__ xh,
    const _Float16* __restrict__ wb,   // wr1h @0, wq1h @16384
    const float* __restrict__ b1,
    _Float16* __restrict__ h, int N)
{
    const int w  = threadIdx.x >> 6;
    const int l  = threadIdx.x & 63;
    const int lr = l & 15;
    const int kg = l >> 4;
    const int base = blockIdx.x * 128 + w * 32;
    const int r0 = min(base + lr,      N - 1);
    const int r1 = min(base + 16 + lr, N - 1);

    f4 acc[2][8];
#pragma unroll
    for (int s = 0; s < 2; ++s)
#pragma unroll
        for (int n = 0; n < 8; ++n) acc[s][n] = 0.f;

#pragma unroll 1
    for (int kk = 0; kk < 8; ++kk) {
        const _Float16* A = (kk < 4) ? aggh : xh;
        const _Float16* B = (kk < 4) ? wb : (wb + 16384);
        const int k0 = (kk & 3) * 32 + kg * 8;
        h8 a0 = *(const h8*)(A + (size_t)r0 * 128 + k0);
        h8 a1 = *(const h8*)(A + (size_t)r1 * 128 + k0);
#pragma unroll
        for (int n = 0; n < 8; ++n) {
            h8 bf = *(const h8*)(B + (size_t)(n * 16 + lr) * 128 + k0);
            acc[0][n] = __builtin_amdgcn_mfma_f32_16x16x32_f16(a0, bf, acc[0][n], 0, 0, 0);
            acc[1][n] = __builtin_amdgcn_mfma_f32_16x16x32_f16(a1, bf, acc[1][n], 0, 0, 0);
        }
    }

    const int ro = kg * 4;   // D: row = (l>>4)*4 + j, col = l&15
#pragma unroll
    for (int s = 0; s < 2; ++s)
#pragma unroll
        for (int n = 0; n < 8; ++n) {
            const int col = n * 16 + lr;
            const float bias = b1[col];
#pragma unroll
            for (int j = 0; j < 4; ++j) {
                int r = base + s * 16 + ro + j;
                if (r < N)
                    h[(size_t)r * 128 + col] = (_Float16)fmaxf(acc[s][n][j] + bias, 0.f);
            }
        }
}

// ----------------------- MFMA GEMM 2 (K=128 split) -------------------------
// cols 0..63 -> hr(f16) = h@Wr2^T ; cols 64..127 -> out(f32) = h@Wq2^T + b2
__global__ __launch_bounds__(256) void mfma_gemm2(
    const _Float16* __restrict__ h,
    const _Float16* __restrict__ wb2,  // wr2h @0, wq2h @8192 (contiguous 128x128)
    const float* __restrict__ b2,
    _Float16* __restrict__ hrh, float* __restrict__ outp, int N)
{
    const int w  = threadIdx.x >> 6;
    const int l  = threadIdx.x & 63;
    const int lr = l & 15;
    const int kg = l >> 4;
    const int base = blockIdx.x * 128 + w * 32;
    const int r0 = min(base + lr,      N - 1);
    const int r1 = min(base + 16 + lr, N - 1);

    f4 acc[2][8];
#pragma unroll
    for (int s = 0; s < 2; ++s)
#pragma unroll
        for (int n = 0; n < 8; ++n) acc[s][n] = 0.f;

#pragma unroll 1
    for (int kk = 0; kk < 4; ++kk) {
        const int k0 = kk * 32 + kg * 8;
        h8 a0 = *(const h8*)(h + (size_t)r0 * 128 + k0);
        h8 a1 = *(const h8*)(h + (size_t)r1 * 128 + k0);
#pragma unroll
        for (int n = 0; n < 8; ++n) {
            h8 bf = *(const h8*)(wb2 + (size_t)(n * 16 + lr) * 128 + k0);
            acc[0][n] = __builtin_amdgcn_mfma_f32_16x16x32_f16(a0, bf, acc[0][n], 0, 0, 0);
            acc[1][n] = __builtin_amdgcn_mfma_f32_16x16x32_f16(a1, bf, acc[1][n], 0, 0, 0);
        }
    }

    const int ro = kg * 4;
#pragma unroll
    for (int s = 0; s < 2; ++s)
#pragma unroll
        for (int n = 0; n < 8; ++n) {
            const int col = n * 16 + lr;
#pragma unroll
            for (int j = 0; j < 4; ++j) {
                int r = base + s * 16 + ro + j;
                if (r < N) {
                    if (n < 4) {
                        hrh[(size_t)r * 64 + col] = (_Float16)acc[s][n][j];
                    } else {
                        outp[(size_t)r * 64 + (col - 64)] = acc[s][n][j] + b2[col - 64];
                    }
                }
            }
        }
}

extern "C" void kernel_launch(void* const* d_in, const int* in_sizes, int n_in,
                              void* d_out, int out_size, void* d_ws, size_t ws_size,
                              hipStream_t stream)
{
    const float* x       = (const float*)d_in[0];
    const int*   ei      = (const int*)d_in[1];
    const float* w_rel1  = (const float*)d_in[2];
    const float* b_rel1  = (const float*)d_in[3];
    const float* w_root1 = (const float*)d_in[4];
    const float* w_rel2  = (const float*)d_in[5];
    const float* b_rel2  = (const float*)d_in[6];
    const float* w_root2 = (const float*)d_in[7];
    float* out = (float*)d_out;

    const int N = in_sizes[0] / 128;
    const int E = in_sizes[1] / 2;
    const int* src = ei;        // edge_index[0]
    const int* dst = ei + E;    // edge_index[1]

    // workspace (~97 MB), all f16 tensors [row][feat]:
    //   xh [N*128] | aggh [N*128] (hr aliases it) | h [N*128] | wbuf [49152]
    //   | srcs [E] | rank [E] | row_ptr [N+1] | cnt [N*CPAD] | blk_sum [1024]
    _Float16* xh    = (_Float16*)d_ws;
    _Float16* aggh  = xh + (size_t)N * 128;
    _Float16* hbuf  = aggh + (size_t)N * 128;
    _Float16* hrh   = aggh;                         // alias: aggh dead after gemm1
    _Float16* wbuf  = hbuf + (size_t)N * 128;
    int*      srcs    = (int*)(wbuf + 49152);
    int*      rank    = srcs + E;
    int*      row_ptr = rank + E;
    int*      cnt     = row_ptr + (N + 1);          // N*CPAD ints (6.4 MB)
    int*      blk_sum = cnt + (size_t)N * CPAD;

    const int nb = (N + 255) / 256;
    const int egrid = (E + 255) / 256;

    // ---- f16 staging ----
    wcast<<<(49152 + 255) / 256, 256, 0, stream>>>(w_rel1, w_root1, w_rel2, w_root2, wbuf);
    xcast<<<(N * 128 / 8 + 255) / 256, 256, 0, stream>>>(x, xh, (long)N * 128);

    // ---- CSR build (shared by both layers) ----
    hipMemsetAsync(cnt, 0, (size_t)N * CPAD * sizeof(int), stream);
    hist_rank<<<egrid, 256, 0, stream>>>(dst, cnt, rank, E);
    scan_p1<<<nb, 256, 0, stream>>>(cnt, row_ptr, blk_sum, N);
    scan_p2<<<1, 1024, 0, stream>>>(blk_sum, nb);
    scan_p3<<<nb, 256, 0, stream>>>(row_ptr, blk_sum, N, E);
    fill_csr2<<<egrid, 256, 0, stream>>>(src, dst, rank, row_ptr, srcs, E);

    // 1. aggh = pull-sum xh
    pull_h128<<<(N * 64 + 255) / 256, 256, 0, stream>>>(
        (const unsigned*)xh, row_ptr, srcs, (unsigned*)aggh, N);

    // 2/3. MFMA GEMMs
    {
        int grid = (N + 127) / 128;
        mfma_gemm1<<<grid, 256, 0, stream>>>(aggh, xh, wbuf, b_rel1, hbuf, N);
        mfma_gemm2<<<grid, 256, 0, stream>>>(hbuf, wbuf + 32768, b_rel2, hrh, out, N);
    }

    // 4. out += pull-sum hr
    pull_add_h64<<<(N * 32 + 255) / 256, 256, 0, stream>>>(
        (const unsigned*)hrh, row_ptr, srcs, out, N);
}

// Round 9
// 312.139 us; speedup vs baseline: 61.8325x; 1.0155x over previous
//
#include <hip/hip_runtime.h>

// GraphConv x2, CSR-pull + f16 MFMA GEMMs (R9):
//   wcast/xcast -> f16 staging
//   CSR build: hist_rank (line-padded counters) -> 3-phase scan -> atomic-free fill
//   pull_h128: aggh(f16) = sum xh[srcs]   [2 rows/instr, 8B/lane, 8-edge unroll]
//   mfma_gemm1: h(f16) = relu(aggh@Wr1^T + xh@Wq1^T + b1)   [K=256 dual, MFMA]
//   mfma_gemm2: hr(f16) = h@Wr2^T ; out(f32) = h@Wq2^T + b2 [K=128, MFMA]
//   pull_add_h64: out += sum hr[srcs]     [4 rows/instr, 8B/lane, 8-edge unroll]
//
// R9 rationale: pull_h128 was top (70 us, 2.95 TB/s fetch-path, VALUBusy 37%)
// — one 256B gather instr per edge with only 4 loads in flight per wave =
// latency x parallelism bound (~1 instr / 53 cy / CU), ~2x below the fetch
// ceiling. Widened to 8B/lane with 2 (resp. 4) rows per instruction and
// 8-edge unroll -> 2x MLP at identical fetch volume; cross-lane shfl_xor
// combines partial sums per node.

typedef float f4 __attribute__((ext_vector_type(4)));
typedef _Float16 h8 __attribute__((ext_vector_type(8)));
typedef _Float16 h2 __attribute__((ext_vector_type(2)));

#define CPAD 16   // counters padded to one per 64B cache line

__device__ __forceinline__ float2 h2f(unsigned u) {
    h2 p = __builtin_bit_cast(h2, u);
    float2 r; r.x = (float)p[0]; r.y = (float)p[1];
    return r;
}
__device__ __forceinline__ unsigned f2h(float a, float b) {
    h2 p; p[0] = (_Float16)a; p[1] = (_Float16)b;
    return __builtin_bit_cast(unsigned, p);
}

// ---------------------------- casts ----------------------------------------
// wbuf layout (halves): wr1h @0 [128x128] | wq1h @16384 | wr2h @32768 [64x128]
// | wq2h @40960  (total 49152)
__global__ void wcast(const float* __restrict__ wr1, const float* __restrict__ wq1,
                      const float* __restrict__ wr2, const float* __restrict__ wq2,
                      _Float16* __restrict__ wb)
{
    int i = blockIdx.x * 256 + threadIdx.x;
    if (i < 16384)      wb[i] = (_Float16)wr1[i];
    else if (i < 32768) wb[i] = (_Float16)wq1[i - 16384];
    else if (i < 40960) wb[i] = (_Float16)wr2[i - 32768];
    else if (i < 49152) wb[i] = (_Float16)wq2[i - 40960];
}

__global__ void xcast(const float* __restrict__ x, _Float16* __restrict__ xh,
                      long n)   // n = N*128, multiple of 8
{
    long i = (long)(blockIdx.x * 256 + threadIdx.x) * 8;
    if (i >= n) return;
    f4 a = *(const f4*)(x + i);
    f4 b = *(const f4*)(x + i + 4);
    h8 o;
    o[0] = (_Float16)a[0]; o[1] = (_Float16)a[1];
    o[2] = (_Float16)a[2]; o[3] = (_Float16)a[3];
    o[4] = (_Float16)b[0]; o[5] = (_Float16)b[1];
    o[6] = (_Float16)b[2]; o[7] = (_Float16)b[3];
    *(h8*)(xh + i) = o;
}

// ---------------------------- CSR build ------------------------------------
__global__ void hist_rank(const int* __restrict__ dst, int* __restrict__ cnt,
                          int* __restrict__ rank, int E)
{
    int e = blockIdx.x * 256 + threadIdx.x;
    if (e < E) rank[e] = atomicAdd(&cnt[(size_t)dst[e] * CPAD], 1);
}

__global__ __launch_bounds__(256) void scan_p1(const int* __restrict__ cnt,
                                               int* __restrict__ row_ptr,
                                               int* __restrict__ blk_sum, int N)
{
    __shared__ int ts[256];
    const int tid = threadIdx.x;
    const int i = blockIdx.x * 256 + tid;
    int v = (i < N) ? cnt[(size_t)i * CPAD] : 0;
    ts[tid] = v;
    __syncthreads();
#pragma unroll
    for (int off = 1; off < 256; off <<= 1) {
        int add = (tid >= off) ? ts[tid - off] : 0;
        __syncthreads();
        ts[tid] += add;
        __syncthreads();
    }
    if (i < N) row_ptr[i] = ts[tid] - v;
    if (tid == 255) blk_sum[blockIdx.x] = ts[255];
}

__global__ __launch_bounds__(1024) void scan_p2(int* __restrict__ blk_sum, int nb)
{
    __shared__ int ts[1024];
    const int tid = threadIdx.x;
    int v = (tid < nb) ? blk_sum[tid] : 0;
    ts[tid] = v;
    __syncthreads();
#pragma unroll
    for (int off = 1; off < 1024; off <<= 1) {
        int add = (tid >= off) ? ts[tid - off] : 0;
        __syncthreads();
        ts[tid] += add;
        __syncthreads();
    }
    if (tid < nb) blk_sum[tid] = ts[tid] - v;
}

__global__ __launch_bounds__(256) void scan_p3(int* __restrict__ row_ptr,
                                               const int* __restrict__ blk_sum,
                                               int N, int E)
{
    const int i = blockIdx.x * 256 + threadIdx.x;
    if (i < N) row_ptr[i] += blk_sum[blockIdx.x];
    if (i == 0) row_ptr[N] = E;
}

__global__ void fill_csr2(const int* __restrict__ src, const int* __restrict__ dst,
                          const int* __restrict__ rank,
                          const int* __restrict__ row_ptr,
                          int* __restrict__ srcs, int E)
{
    int e = blockIdx.x * 256 + threadIdx.x;
    if (e < E) srcs[row_ptr[dst[e]] + rank[e]] = src[e];
}

// --------------------------- pull kernels ----------------------------------
// one wave per node. lane = (half, col): half = edge-of-pair, col = uint2 col.
// Per VMEM instr: 2 rows x 256B. Main loop = 8 edges (4 paired loads in flight).
__global__ __launch_bounds__(256) void pull_h128(const uint2* __restrict__ xh4,
                                                 const int* __restrict__ row_ptr,
                                                 const int* __restrict__ srcs,
                                                 uint2* __restrict__ aggh4, int N)
{
    const int w    = (blockIdx.x * 256 + threadIdx.x) >> 6;
    const int l    = threadIdx.x & 63;
    const int half = l >> 5;        // which edge of the pair
    const int col  = l & 31;        // uint2 col -> feats 4c..4c+3
    if (w >= N) return;
    const int beg = row_ptr[w], end = row_ptr[w + 1];
    float a0 = 0.f, a1 = 0.f, a2 = 0.f, a3 = 0.f;
    int j = beg;
    for (; j + 7 < end; j += 8) {
        int s0 = srcs[j + 0 + half], s1 = srcs[j + 2 + half];
        int s2 = srcs[j + 4 + half], s3 = srcs[j + 6 + half];
        uint2 u0 = xh4[(size_t)s0 * 32 + col];
        uint2 u1 = xh4[(size_t)s1 * 32 + col];
        uint2 u2 = xh4[(size_t)s2 * 32 + col];
        uint2 u3 = xh4[(size_t)s3 * 32 + col];
        float2 p;
        p = h2f(u0.x); a0 += p.x; a1 += p.y;  p = h2f(u0.y); a2 += p.x; a3 += p.y;
        p = h2f(u1.x); a0 += p.x; a1 += p.y;  p = h2f(u1.y); a2 += p.x; a3 += p.y;
        p = h2f(u2.x); a0 += p.x; a1 += p.y;  p = h2f(u2.y); a2 += p.x; a3 += p.y;
        p = h2f(u3.x); a0 += p.x; a1 += p.y;  p = h2f(u3.y); a2 += p.x; a3 += p.y;
    }
    for (; j < end; j += 2) {                      // paired tail, predicated
        int jj = j + half;
        float m = (jj < end) ? 1.f : 0.f;
        int s = srcs[(jj < end) ? jj : (end - 1)];
        uint2 u = xh4[(size_t)s * 32 + col];
        float2 p;
        p = h2f(u.x); a0 += m * p.x; a1 += m * p.y;
        p = h2f(u.y); a2 += m * p.x; a3 += m * p.y;
    }
    // combine the two halves
    a0 += __shfl_xor(a0, 32); a1 += __shfl_xor(a1, 32);
    a2 += __shfl_xor(a2, 32); a3 += __shfl_xor(a3, 32);
    if (half == 0) {
        uint2 o; o.x = f2h(a0, a1); o.y = f2h(a2, a3);
        aggh4[(size_t)w * 32 + col] = o;
    }
}

// one wave per node. lane = (q, col): q = edge-of-quad, col = uint2 col (16/row).
// Per VMEM instr: 4 rows x 128B. Main loop = 8 edges (2 quad loads in flight).
__global__ __launch_bounds__(256) void pull_add_h64(const uint2* __restrict__ hr4,
                                                    const int* __restrict__ row_ptr,
                                                    const int* __restrict__ srcs,
                                                    float* __restrict__ out, int N)
{
    const int w   = (blockIdx.x * 256 + threadIdx.x) >> 6;
    const int l   = threadIdx.x & 63;
    const int q   = l >> 4;         // which edge of the quad
    const int col = l & 15;         // uint2 col -> feats 4c..4c+3
    if (w >= N) return;
    const int beg = row_ptr[w], end = row_ptr[w + 1];
    float a0 = 0.f, a1 = 0.f, a2 = 0.f, a3 = 0.f;
    int j = beg;
    for (; j + 7 < end; j += 8) {
        int s0 = srcs[j + q], s1 = srcs[j + 4 + q];
        uint2 u0 = hr4[(size_t)s0 * 16 + col];
        uint2 u1 = hr4[(size_t)s1 * 16 + col];
        float2 p;
        p = h2f(u0.x); a0 += p.x; a1 += p.y;  p = h2f(u0.y); a2 += p.x; a3 += p.y;
        p = h2f(u1.x); a0 += p.x; a1 += p.y;  p = h2f(u1.y); a2 += p.x; a3 += p.y;
    }
    for (; j < end; j += 4) {                      // quad tail, predicated
        int jj = j + q;
        float m = (jj < end) ? 1.f : 0.f;
        int s = srcs[(jj < end) ? jj : (end - 1)];
        uint2 u = hr4[(size_t)s * 16 + col];
        float2 p;
        p = h2f(u.x); a0 += m * p.x; a1 += m * p.y;
        p = h2f(u.y); a2 += m * p.x; a3 += m * p.y;
    }
    // combine the four quads
    a0 += __shfl_xor(a0, 16); a1 += __shfl_xor(a1, 16);
    a2 += __shfl_xor(a2, 16); a3 += __shfl_xor(a3, 16);
    a0 += __shfl_xor(a0, 32); a1 += __shfl_xor(a1, 32);
    a2 += __shfl_xor(a2, 32); a3 += __shfl_xor(a3, 32);
    if (q == 0) {
        f4* po = (f4*)out + (size_t)w * 16 + col;
        f4 cur = *po;
        cur[0] += a0; cur[1] += a1; cur[2] += a2; cur[3] += a3;
        *po = cur;
    }
}

// ----------------------- MFMA GEMM 1 (K=256 dual) --------------------------
// h = relu([aggh|xh] @ [Wr1|Wq1]^T + b1). 4 waves/block, 32 rows/wave,
// full 128 output cols per wave. acc f4[2][8]; frags direct from global.
__global__ __launch_bounds__(256) void mfma_gemm1(
    const _Float16* __restrict__ aggh, const _Float16* __restrict__ xh,
    const _Float16* __restrict__ wb,   // wr1h @0, wq1h @16384
    const float* __restrict__ b1,
    _Float16* __restrict__ h, int N)
{
    const int w  = threadIdx.x >> 6;
    const int l  = threadIdx.x & 63;
    const int lr = l & 15;
    const int kg = l >> 4;
    const int base = blockIdx.x * 128 + w * 32;
    const int r0 = min(base + lr,      N - 1);
    const int r1 = min(base + 16 + lr, N - 1);

    f4 acc[2][8];
#pragma unroll
    for (int s = 0; s < 2; ++s)
#pragma unroll
        for (int n = 0; n < 8; ++n) acc[s][n] = 0.f;

#pragma unroll 1
    for (int kk = 0; kk < 8; ++kk) {
        const _Float16* A = (kk < 4) ? aggh : xh;
        const _Float16* B = (kk < 4) ? wb : (wb + 16384);
        const int k0 = (kk & 3) * 32 + kg * 8;
        h8 a0 = *(const h8*)(A + (size_t)r0 * 128 + k0);
        h8 a1 = *(const h8*)(A + (size_t)r1 * 128 + k0);
#pragma unroll
        for (int n = 0; n < 8; ++n) {
            h8 bf = *(const h8*)(B + (size_t)(n * 16 + lr) * 128 + k0);
            acc[0][n] = __builtin_amdgcn_mfma_f32_16x16x32_f16(a0, bf, acc[0][n], 0, 0, 0);
            acc[1][n] = __builtin_amdgcn_mfma_f32_16x16x32_f16(a1, bf, acc[1][n], 0, 0, 0);
        }
    }

    const int ro = kg * 4;   // D: row = (l>>4)*4 + j, col = l&15
#pragma unroll
    for (int s = 0; s < 2; ++s)
#pragma unroll
        for (int n = 0; n < 8; ++n) {
            const int col = n * 16 + lr;
            const float bias = b1[col];
#pragma unroll
            for (int j = 0; j < 4; ++j) {
                int r = base + s * 16 + ro + j;
                if (r < N)
                    h[(size_t)r * 128 + col] = (_Float16)fmaxf(acc[s][n][j] + bias, 0.f);
            }
        }
}

// ----------------------- MFMA GEMM 2 (K=128 split) -------------------------
// cols 0..63 -> hr(f16) = h@Wr2^T ; cols 64..127 -> out(f32) = h@Wq2^T + b2
__global__ __launch_bounds__(256) void mfma_gemm2(
    const _Float16* __restrict__ h,
    const _Float16* __restrict__ wb2,  // wr2h @0, wq2h @8192 (contiguous 128x128)
    const float* __restrict__ b2,
    _Float16* __restrict__ hrh, float* __restrict__ outp, int N)
{
    const int w  = threadIdx.x >> 6;
    const int l  = threadIdx.x & 63;
    const int lr = l & 15;
    const int kg = l >> 4;
    const int base = blockIdx.x * 128 + w * 32;
    const int r0 = min(base + lr,      N - 1);
    const int r1 = min(base + 16 + lr, N - 1);

    f4 acc[2][8];
#pragma unroll
    for (int s = 0; s < 2; ++s)
#pragma unroll
        for (int n = 0; n < 8; ++n) acc[s][n] = 0.f;

#pragma unroll 1
    for (int kk = 0; kk < 4; ++kk) {
        const int k0 = kk * 32 + kg * 8;
        h8 a0 = *(const h8*)(h + (size_t)r0 * 128 + k0);
        h8 a1 = *(const h8*)(h + (size_t)r1 * 128 + k0);
#pragma unroll
        for (int n = 0; n < 8; ++n) {
            h8 bf = *(const h8*)(wb2 + (size_t)(n * 16 + lr) * 128 + k0);
            acc[0][n] = __builtin_amdgcn_mfma_f32_16x16x32_f16(a0, bf, acc[0][n], 0, 0, 0);
            acc[1][n] = __builtin_amdgcn_mfma_f32_16x16x32_f16(a1, bf, acc[1][n], 0, 0, 0);
        }
    }

    const int ro = kg * 4;
#pragma unroll
    for (int s = 0; s < 2; ++s)
#pragma unroll
        for (int n = 0; n < 8; ++n) {
            const int col = n * 16 + lr;
#pragma unroll
            for (int j = 0; j < 4; ++j) {
                int r = base + s * 16 + ro + j;
                if (r < N) {
                    if (n < 4) {
                        hrh[(size_t)r * 64 + col] = (_Float16)acc[s][n][j];
                    } else {
                        outp[(size_t)r * 64 + (col - 64)] = acc[s][n][j] + b2[col - 64];
                    }
                }
            }
        }
}

extern "C" void kernel_launch(void* const* d_in, const int* in_sizes, int n_in,
                              void* d_out, int out_size, void* d_ws, size_t ws_size,
                              hipStream_t stream)
{
    const float* x       = (const float*)d_in[0];
    const int*   ei      = (const int*)d_in[1];
    const float* w_rel1  = (const float*)d_in[2];
    const float* b_rel1  = (const float*)d_in[3];
    const float* w_root1 = (const float*)d_in[4];
    const float* w_rel2  = (const float*)d_in[5];
    const float* b_rel2  = (const float*)d_in[6];
    const float* w_root2 = (const float*)d_in[7];
    float* out = (float*)d_out;

    const int N = in_sizes[0] / 128;
    const int E = in_sizes[1] / 2;
    const int* src = ei;        // edge_index[0]
    const int* dst = ei + E;    // edge_index[1]

    // workspace (~97 MB), all f16 tensors [row][feat]:
    //   xh [N*128] | aggh [N*128] (hr aliases it) | h [N*128] | wbuf [49152]
    //   | srcs [E] | rank [E] | row_ptr [N+1] | cnt [N*CPAD] | blk_sum [1024]
    _Float16* xh    = (_Float16*)d_ws;
    _Float16* aggh  = xh + (size_t)N * 128;
    _Float16* hbuf  = aggh + (size_t)N * 128;
    _Float16* hrh   = aggh;                         // alias: aggh dead after gemm1
    _Float16* wbuf  = hbuf + (size_t)N * 128;
    int*      srcs    = (int*)(wbuf + 49152);
    int*      rank    = srcs + E;
    int*      row_ptr = rank + E;
    int*      cnt     = row_ptr + (N + 1);          // N*CPAD ints (6.4 MB)
    int*      blk_sum = cnt + (size_t)N * CPAD;

    const int nb = (N + 255) / 256;
    const int egrid = (E + 255) / 256;

    // ---- f16 staging ----
    wcast<<<(49152 + 255) / 256, 256, 0, stream>>>(w_rel1, w_root1, w_rel2, w_root2, wbuf);
    xcast<<<(N * 128 / 8 + 255) / 256, 256, 0, stream>>>(x, xh, (long)N * 128);

    // ---- CSR build (shared by both layers) ----
    hipMemsetAsync(cnt, 0, (size_t)N * CPAD * sizeof(int), stream);
    hist_rank<<<egrid, 256, 0, stream>>>(dst, cnt, rank, E);
    scan_p1<<<nb, 256, 0, stream>>>(cnt, row_ptr, blk_sum, N);
    scan_p2<<<1, 1024, 0, stream>>>(blk_sum, nb);
    scan_p3<<<nb, 256, 0, stream>>>(row_ptr, blk_sum, N, E);
    fill_csr2<<<egrid, 256, 0, stream>>>(src, dst, rank, row_ptr, srcs, E);

    // 1. aggh = pull-sum xh
    pull_h128<<<(N * 64 + 255) / 256, 256, 0, stream>>>(
        (const uint2*)xh, row_ptr, srcs, (uint2*)aggh, N);

    // 2/3. MFMA GEMMs
    {
        int grid = (N + 127) / 128;
        mfma_gemm1<<<grid, 256, 0, stream>>>(aggh, xh, wbuf, b_rel1, hbuf, N);
        mfma_gemm2<<<grid, 256, 0, stream>>>(hbuf, wbuf + 32768, b_rel2, hrh, out, N);
    }

    // 4. out += pull-sum hr
    pull_add_h64<<<(N * 64 + 255) / 256, 256, 0, stream>>>(
        (const uint2*)hrh, row_ptr, srcs, out, N);
}